// Round 1
// baseline (2415.474 us; speedup 1.0000x reference)
//
#include <hip/hip_runtime.h>
#include <math.h>

#define NN 100000
#define NE 3200000
#define NG 512
#define D 16
#define SLOPE 0.01f

__device__ __forceinline__ float leakyf(float x){ return x >= 0.0f ? x : SLOPE*x; }
__device__ __forceinline__ float dleakyf(float x){ return x >= 0.0f ? 1.0f : SLOPE; }

__global__ void k_fill(float* __restrict__ p, int n, float v){
  int i = blockIdx.x*blockDim.x + threadIdx.x;
  if (i < n) p[i] = v;
}

// K1: edge distances + weighted in-degree (deg init to 1.0 for self loop)
__global__ void k_edge_dist(const float* __restrict__ pos, const int* __restrict__ ei,
                            float* __restrict__ w, float* __restrict__ deg){
  int e = blockIdx.x*blockDim.x + threadIdx.x;
  if (e >= NE) return;
  int r = ei[e], c = ei[NE+e];
  float dx = pos[3*r+0]-pos[3*c+0];
  float dy = pos[3*r+1]-pos[3*c+1];
  float dz = pos[3*r+2]-pos[3*c+2];
  float we = sqrtf(dx*dx+dy*dy+dz*dz);
  w[e] = we;
  atomicAdd(&deg[c], we);
}

// K2: dinv = deg^-1/2 (in place), y1 = emb[z] @ W1
__global__ void k_node_y1(const float* __restrict__ emb, const int* __restrict__ z,
                          const float* __restrict__ W1, float* __restrict__ dinv,
                          float* __restrict__ y1){
  __shared__ float sW[D*D];
  for (int i = threadIdx.x; i < D*D; i += blockDim.x) sW[i] = W1[i];
  __syncthreads();
  int n = blockIdx.x*blockDim.x + threadIdx.x;
  if (n >= NN) return;
  float dv = 1.0f / sqrtf(dinv[n]);   // dinv currently holds deg (>=1)
  dinv[n] = dv;
  const float* em = emb + z[n]*D;
  float h[D];
  #pragma unroll
  for (int j=0;j<D;j++) h[j] = em[j];
  #pragma unroll
  for (int k=0;k<D;k++){
    float s = 0.0f;
    #pragma unroll
    for (int j=0;j<D;j++) s += h[j]*sW[j*D+k];
    y1[n*D+k] = s;
  }
}

// K3/K5: conv scatter  out[c,:] += y[r,:] * (dinv[r]*w*dinv[c]); 16 lanes per edge
__global__ void k_conv_scatter(const int* __restrict__ ei, const float* __restrict__ w,
                               const float* __restrict__ dinv, const float* __restrict__ y,
                               float* __restrict__ out){
  int t = blockIdx.x*blockDim.x + threadIdx.x;
  int e = t >> 4, k = t & 15;
  if (e >= NE) return;
  int r = ei[e], c = ei[NE+e];
  float nrm = dinv[r]*w[e]*dinv[c];
  atomicAdd(&out[c*D+k], y[r*D+k]*nrm);
}

// K4: finish conv1 (self loop + bias), h1=leaky, h2=leaky(h1@Wl1+bl1), y2=h2@W2, masks
__global__ void k_node_mid(const float* __restrict__ u1acc, const float* __restrict__ y1,
                           const float* __restrict__ dinv,
                           const float* __restrict__ b1, const float* __restrict__ Wl1,
                           const float* __restrict__ bl1, const float* __restrict__ W2,
                           float* __restrict__ y2, unsigned* __restrict__ masks){
  __shared__ float sWl1[D*D], sW2[D*D], sb1[D], sbl1[D];
  for (int i = threadIdx.x; i < D*D; i += blockDim.x){ sWl1[i] = Wl1[i]; sW2[i] = W2[i]; }
  if (threadIdx.x < D){ sb1[threadIdx.x] = b1[threadIdx.x]; sbl1[threadIdx.x] = bl1[threadIdx.x]; }
  __syncthreads();
  int n = blockIdx.x*blockDim.x + threadIdx.x;
  if (n >= NN) return;
  float dv = dinv[n], d2 = dv*dv;
  unsigned m = 0;
  float h1[D];
  #pragma unroll
  for (int k=0;k<D;k++){
    float u = u1acc[n*D+k] + y1[n*D+k]*d2 + sb1[k];
    if (u >= 0.0f) m |= (1u<<k);
    h1[k] = leakyf(u);
  }
  float h2[D];
  #pragma unroll
  for (int j=0;j<D;j++){
    float u = sbl1[j];
    #pragma unroll
    for (int k=0;k<D;k++) u += h1[k]*sWl1[k*D+j];
    if (u >= 0.0f) m |= (1u<<(16+j));
    h2[j] = leakyf(u);
  }
  #pragma unroll
  for (int k=0;k<D;k++){
    float s = 0.0f;
    #pragma unroll
    for (int j=0;j<D;j++) s += h2[j]*sW2[j*D+k];
    y2[n*D+k] = s;
  }
  masks[n] = m;
}

// K6: finish conv2, MLP head, E accumulation; backward node chain to du3, gdiag = du3.y2
__global__ void k_node_out(const float* __restrict__ u3acc, const float* __restrict__ y2,
                           const float* __restrict__ dinv, const int* __restrict__ batch,
                           const float* __restrict__ b2, const float* __restrict__ Wl2,
                           const float* __restrict__ bl2, const float* __restrict__ Wl3,
                           const float* __restrict__ bl3,
                           float* __restrict__ Eout, float* __restrict__ du3,
                           float* __restrict__ gdiag){
  __shared__ float sb2[D], sWl2[D*4], sbl2[4], sWl3[4], sbl3;
  if (threadIdx.x < D) sb2[threadIdx.x] = b2[threadIdx.x];
  if (threadIdx.x < D*4) sWl2[threadIdx.x] = Wl2[threadIdx.x];
  if (threadIdx.x < 4){ sbl2[threadIdx.x] = bl2[threadIdx.x]; sWl3[threadIdx.x] = Wl3[threadIdx.x]; }
  if (threadIdx.x == 0) sbl3 = bl3[0];
  __syncthreads();
  int n = blockIdx.x*blockDim.x + threadIdx.x;
  if (n >= NN) return;
  float dv = dinv[n], d2 = dv*dv;
  float u3[D], h3[D];
  #pragma unroll
  for (int k=0;k<D;k++){
    u3[k] = u3acc[n*D+k] + y2[n*D+k]*d2 + sb2[k];
    h3[k] = leakyf(u3[k]);
  }
  float u4[4], h4[4];
  #pragma unroll
  for (int j=0;j<4;j++){
    float u = sbl2[j];
    #pragma unroll
    for (int k=0;k<D;k++) u += h3[k]*sWl2[k*4+j];
    u4[j] = u; h4[j] = leakyf(u);
  }
  float u5 = sbl3;
  #pragma unroll
  for (int j=0;j<4;j++) u5 += h4[j]*sWl3[j];
  float h5 = leakyf(u5);
  atomicAdd(&Eout[batch[n]], h5);
  // backward (cotangent of h5 is 1)
  float du5 = dleakyf(u5);
  float du4[4];
  #pragma unroll
  for (int j=0;j<4;j++) du4[j] = du5*sWl3[j]*dleakyf(u4[j]);
  float gd = 0.0f;
  #pragma unroll
  for (int k=0;k<D;k++){
    float g = 0.0f;
    #pragma unroll
    for (int j=0;j<4;j++) g += du4[j]*sWl2[k*4+j];
    float d3 = g*dleakyf(u3[k]);
    du3[n*D+k] = d3;
    gd += d3*y2[n*D+k];
  }
  gdiag[n] = gd;
}

// K7: layer-2 edge backward: gnorm2, g_y2 transpose scatter, gdinv atomics
__global__ void k_edge_bwd2(const int* __restrict__ ei, const float* __restrict__ w,
                            const float* __restrict__ dinv, const float* __restrict__ y2,
                            const float* __restrict__ du3, float* __restrict__ gy2,
                            float* __restrict__ gn, float* __restrict__ gdinv){
  int t = blockIdx.x*blockDim.x + threadIdx.x;
  int e = t >> 4, k = t & 15;
  if (e >= NE) return;
  int r = ei[e], c = ei[NE+e];
  float we = w[e], dr = dinv[r], dc = dinv[c];
  float d3 = du3[c*D+k];
  float p = d3 * y2[r*D+k];
  atomicAdd(&gy2[r*D+k], dr*we*dc*d3);
  p += __shfl_xor(p, 8, 16);
  p += __shfl_xor(p, 4, 16);
  p += __shfl_xor(p, 2, 16);
  p += __shfl_xor(p, 1, 16);
  if (k == 0){
    gn[e] = p;
    atomicAdd(&gdinv[r], p*we*dc);
    atomicAdd(&gdinv[c], p*we*dr);
  }
}

// K8: node backward mid: gy2(+selfloop) -> du2 -> du1, gdiag += du1.y1
__global__ void k_node_bwdmid(const float* __restrict__ gy2, const float* __restrict__ du3,
                              const float* __restrict__ y1, const float* __restrict__ dinv,
                              const unsigned* __restrict__ masks,
                              const float* __restrict__ W2, const float* __restrict__ Wl1,
                              float* __restrict__ du1, float* __restrict__ gdiag){
  __shared__ float sW2[D*D], sWl1[D*D];
  for (int i = threadIdx.x; i < D*D; i += blockDim.x){ sW2[i] = W2[i]; sWl1[i] = Wl1[i]; }
  __syncthreads();
  int n = blockIdx.x*blockDim.x + threadIdx.x;
  if (n >= NN) return;
  float dv = dinv[n], d2 = dv*dv;
  unsigned m = masks[n];
  float gy[D];
  #pragma unroll
  for (int k=0;k<D;k++) gy[k] = gy2[n*D+k] + d2*du3[n*D+k];
  float du2[D];
  #pragma unroll
  for (int k=0;k<D;k++){
    float g = 0.0f;
    #pragma unroll
    for (int j=0;j<D;j++) g += gy[j]*sW2[k*D+j];
    du2[k] = g * (((m>>(16+k))&1u) ? 1.0f : SLOPE);
  }
  float gd = gdiag[n];
  #pragma unroll
  for (int k=0;k<D;k++){
    float g = 0.0f;
    #pragma unroll
    for (int j=0;j<D;j++) g += du2[j]*sWl1[k*D+j];
    float d1 = g * (((m>>k)&1u) ? 1.0f : SLOPE);
    du1[n*D+k] = d1;
    gd += d1*y1[n*D+k];
  }
  gdiag[n] = gd;
}

// K9: layer-1 edge backward: gnorm1 (accumulate into gn), gdinv atomics
__global__ void k_edge_bwd1(const int* __restrict__ ei, const float* __restrict__ w,
                            const float* __restrict__ dinv, const float* __restrict__ y1,
                            const float* __restrict__ du1,
                            float* __restrict__ gn, float* __restrict__ gdinv){
  int t = blockIdx.x*blockDim.x + threadIdx.x;
  int e = t >> 4, k = t & 15;
  if (e >= NE) return;
  int r = ei[e], c = ei[NE+e];
  float we = w[e], dr = dinv[r], dc = dinv[c];
  float p = du1[c*D+k] * y1[r*D+k];
  p += __shfl_xor(p, 8, 16);
  p += __shfl_xor(p, 4, 16);
  p += __shfl_xor(p, 2, 16);
  p += __shfl_xor(p, 1, 16);
  if (k == 0){
    gn[e] += p;
    atomicAdd(&gdinv[r], p*we*dc);
    atomicAdd(&gdinv[c], p*we*dr);
  }
}

// K10: gdeg = -0.5*dinv^3*(gdinv + 2*dinv*gdiag)
__global__ void k_node_gdeg(const float* __restrict__ dinv, const float* __restrict__ gdinv,
                            const float* __restrict__ gdiag, float* __restrict__ gdeg){
  int n = blockIdx.x*blockDim.x + threadIdx.x;
  if (n >= NN) return;
  float dv = dinv[n];
  float g = gdinv[n] + 2.0f*dv*gdiag[n];
  gdeg[n] = -0.5f*dv*dv*dv*g;
}

// K11: forces: gw = gn*dinv[r]*dinv[c] + gdeg[c]; F[r] -= gw/w*diff; F[c] += gw/w*diff
__global__ void k_edge_force(const int* __restrict__ ei, const float* __restrict__ pos,
                             const float* __restrict__ w, const float* __restrict__ dinv,
                             const float* __restrict__ gn, const float* __restrict__ gdeg,
                             float* __restrict__ F){
  int e = blockIdx.x*blockDim.x + threadIdx.x;
  if (e >= NE) return;
  int r = ei[e], c = ei[NE+e];
  float we = w[e];
  float gw = gn[e]*dinv[r]*dinv[c] + gdeg[c];
  float coef = gw / we;
  float dx = pos[3*r+0]-pos[3*c+0];
  float dy = pos[3*r+1]-pos[3*c+1];
  float dz = pos[3*r+2]-pos[3*c+2];
  atomicAdd(&F[3*r+0], -coef*dx);
  atomicAdd(&F[3*r+1], -coef*dy);
  atomicAdd(&F[3*r+2], -coef*dz);
  atomicAdd(&F[3*c+0],  coef*dx);
  atomicAdd(&F[3*c+1],  coef*dy);
  atomicAdd(&F[3*c+2],  coef*dz);
}

extern "C" void kernel_launch(void* const* d_in, const int* in_sizes, int n_in,
                              void* d_out, int out_size, void* d_ws, size_t ws_size,
                              hipStream_t stream){
  const float* pos = (const float*)d_in[0];
  const float* emb = (const float*)d_in[1];
  const float* W1  = (const float*)d_in[2];
  const float* b1  = (const float*)d_in[3];
  const float* Wl1 = (const float*)d_in[4];
  const float* bl1 = (const float*)d_in[5];
  const float* W2  = (const float*)d_in[6];
  const float* b2  = (const float*)d_in[7];
  const float* Wl2 = (const float*)d_in[8];
  const float* bl2 = (const float*)d_in[9];
  const float* Wl3 = (const float*)d_in[10];
  const float* bl3 = (const float*)d_in[11];
  const int* z     = (const int*)d_in[12];
  const int* ei    = (const int*)d_in[13];
  const int* batch = (const int*)d_in[14];

  float* ws = (float*)d_ws;
  // layout (floats): w[E] gn[E] dinv[N] gdiag[N] gdeg[N] masks[N] y1[16N] y2[16N]
  //                  du3[16N] bufA[16N] bufB[16N] gy2[16N] gdinv[N]  -> 2E+101N total
  float* w_buf  = ws;
  float* gn_buf = ws + NE;
  float* dinv   = ws + 2*NE;
  float* gdiag  = dinv + NN;
  float* gdeg   = gdiag + NN;
  unsigned* masks = (unsigned*)(gdeg + NN);
  float* y1     = gdeg + 2*NN;
  float* y2     = y1 + 16*NN;
  float* du3    = y2 + 16*NN;
  float* bufA   = du3 + 16*NN;   // u1acc, later du1
  float* bufB   = bufA + 16*NN;  // u3acc
  float* gy2    = bufB + 16*NN;
  float* gdinv  = gy2 + 16*NN;

  float* Eout = (float*)d_out;
  float* F = Eout + NG;

  const int BT = 256;
  int nbN   = (NN + BT - 1)/BT;
  int nbE   = (NE + BT - 1)/BT;
  int nbE16 = (NE*16 + BT - 1)/BT;

  // init: zero [bufA, bufB, gy2, gdinv] (contiguous 49N), zero output, deg = 1.0
  int zn = 49*NN;
  k_fill<<<(zn+BT-1)/BT, BT, 0, stream>>>(bufA, zn, 0.0f);
  k_fill<<<(NG+3*NN+BT-1)/BT, BT, 0, stream>>>(Eout, NG+3*NN, 0.0f);
  k_fill<<<nbN, BT, 0, stream>>>(dinv, NN, 1.0f);

  k_edge_dist<<<nbE, BT, 0, stream>>>(pos, ei, w_buf, dinv);
  k_node_y1<<<nbN, BT, 0, stream>>>(emb, z, W1, dinv, y1);
  k_conv_scatter<<<nbE16, BT, 0, stream>>>(ei, w_buf, dinv, y1, bufA);
  k_node_mid<<<nbN, BT, 0, stream>>>(bufA, y1, dinv, b1, Wl1, bl1, W2, y2, masks);
  k_conv_scatter<<<nbE16, BT, 0, stream>>>(ei, w_buf, dinv, y2, bufB);
  k_node_out<<<nbN, BT, 0, stream>>>(bufB, y2, dinv, batch, b2, Wl2, bl2, Wl3, bl3, Eout, du3, gdiag);
  k_edge_bwd2<<<nbE16, BT, 0, stream>>>(ei, w_buf, dinv, y2, du3, gy2, gn_buf, gdinv);
  k_node_bwdmid<<<nbN, BT, 0, stream>>>(gy2, du3, y1, dinv, masks, W2, Wl1, bufA, gdiag);
  k_edge_bwd1<<<nbE16, BT, 0, stream>>>(ei, w_buf, dinv, y1, bufA, gn_buf, gdinv);
  k_node_gdeg<<<nbN, BT, 0, stream>>>(dinv, gdinv, gdiag, gdeg);
  k_edge_force<<<nbE, BT, 0, stream>>>(ei, pos, w_buf, dinv, gn_buf, gdeg, F);
}

// Round 2
// 1484.697 us; speedup vs baseline: 1.6269x; 1.6269x over previous
//
#include <hip/hip_runtime.h>
#include <math.h>

#define NN 100000
#define NE 3200000
#define NG 512
#define D 16
#define SLOPE 0.01f
#define BT 256

__device__ __forceinline__ float leakyf(float x){ return x >= 0.0f ? x : SLOPE*x; }
__device__ __forceinline__ float dleakyf(float x){ return x >= 0.0f ? 1.0f : SLOPE; }

__device__ __forceinline__ float red16(float v){
  v += __shfl_xor(v, 8, 16);
  v += __shfl_xor(v, 4, 16);
  v += __shfl_xor(v, 2, 16);
  v += __shfl_xor(v, 1, 16);
  return v;
}

__global__ void k_fill(float* __restrict__ p, int n, float v){
  int i = blockIdx.x*blockDim.x + threadIdx.x;
  if (i < n) p[i] = v;
}

// ---- CSR build ----------------------------------------------------------
__global__ void k_count(const int* __restrict__ ei, int* __restrict__ cnt_row,
                        int* __restrict__ cnt_col){
  int e = blockIdx.x*blockDim.x + threadIdx.x;
  if (e >= NE) return;
  atomicAdd(&cnt_row[ei[e]], 1);
  atomicAdd(&cnt_col[ei[NE+e]], 1);
}

// block sums (grid (nb,2): y=0 row, y=1 col)
__global__ void k_blocksum(const int* __restrict__ cnt_row, const int* __restrict__ cnt_col,
                           int* __restrict__ bsum){
  const int* src = blockIdx.y ? cnt_col : cnt_row;
  __shared__ int s[BT];
  int i = blockIdx.x*BT + threadIdx.x;
  s[threadIdx.x] = (i < NN) ? src[i] : 0;
  __syncthreads();
  for (int off = BT/2; off > 0; off >>= 1){
    if (threadIdx.x < off) s[threadIdx.x] += s[threadIdx.x+off];
    __syncthreads();
  }
  if (threadIdx.x == 0) bsum[blockIdx.y*512 + blockIdx.x] = s[0];
}

// exclusive scan of block sums (grid (1,2), block 512)
__global__ void k_scan_bsum(int* __restrict__ bsum, int nb){
  int* b = bsum + blockIdx.y*512;
  __shared__ int s0[512], s1[512];
  int tid = threadIdx.x;
  int v = (tid < nb) ? b[tid] : 0;
  s0[tid] = v; __syncthreads();
  int rd = 0;
  for (int off = 1; off < 512; off <<= 1){
    int x = rd ? s1[tid] : s0[tid];
    if (tid >= off) x += rd ? s1[tid-off] : s0[tid-off];
    if (rd) s0[tid] = x; else s1[tid] = x;
    __syncthreads();
    rd ^= 1;
  }
  int incl = rd ? s1[tid] : s0[tid];
  if (tid < nb) b[tid] = incl - v;   // exclusive base
}

// per-element exclusive offsets + cursor copies (grid (nb,2))
__global__ void k_offsets(const int* __restrict__ cnt_row, const int* __restrict__ cnt_col,
                          const int* __restrict__ bsum,
                          int* __restrict__ off_row, int* __restrict__ off_col,
                          int* __restrict__ cur_row, int* __restrict__ cur_col){
  const int* src  = blockIdx.y ? cnt_col : cnt_row;
  int* offd = blockIdx.y ? off_col : off_row;
  int* curd = blockIdx.y ? cur_col : cur_row;
  __shared__ int s0[BT], s1[BT];
  int tid = threadIdx.x;
  int i = blockIdx.x*BT + tid;
  int v = (i < NN) ? src[i] : 0;
  s0[tid] = v; __syncthreads();
  int rd = 0;
  for (int off = 1; off < BT; off <<= 1){
    int x = rd ? s1[tid] : s0[tid];
    if (tid >= off) x += rd ? s1[tid-off] : s0[tid-off];
    if (rd) s0[tid] = x; else s1[tid] = x;
    __syncthreads();
    rd ^= 1;
  }
  int incl = rd ? s1[tid] : s0[tid];
  if (i < NN){
    int o = bsum[blockIdx.y*512 + blockIdx.x] + incl - v;
    offd[i] = o; curd[i] = o;
  }
}

// place edges into both CSRs; compute w on the fly
__global__ void k_place(const int* __restrict__ ei, const float* __restrict__ pos,
                        int* __restrict__ cur_row, int* __restrict__ cur_col,
                        int* __restrict__ row_dst, float* __restrict__ row_wf,
                        int* __restrict__ col_src, int* __restrict__ col_rp,
                        float* __restrict__ col_wf){
  int e = blockIdx.x*blockDim.x + threadIdx.x;
  if (e >= NE) return;
  int r = ei[e], c = ei[NE+e];
  float dx = pos[3*r+0]-pos[3*c+0];
  float dy = pos[3*r+1]-pos[3*c+1];
  float dz = pos[3*r+2]-pos[3*c+2];
  float w = sqrtf(dx*dx+dy*dy+dz*dz);
  int p = atomicAdd(&cur_row[r], 1);
  int q = atomicAdd(&cur_col[c], 1);
  row_dst[p] = c; row_wf[p] = w;
  col_src[q] = r; col_rp[q] = p; col_wf[q] = w;
}

// ---- forward ------------------------------------------------------------
// dinv[n] = 1/sqrt(1 + sum_in w)
__global__ void k_dinv(const float* __restrict__ col_wf, const int* __restrict__ off_col,
                       const int* __restrict__ cnt_col, float* __restrict__ dinv){
  int t = blockIdx.x*blockDim.x + threadIdx.x;
  int n = t >> 4, k = t & 15;
  if (n >= NN) return;
  int base = off_col[n], cnt = cnt_col[n];
  float s = 0.f;
  for (int i = k; i < cnt; i += 16) s += col_wf[base+i];
  s = red16(s);
  if (k == 0) dinv[n] = 1.0f / sqrtf(1.0f + s);
}

__global__ void k_y1(const float* __restrict__ emb, const int* __restrict__ z,
                     const float* __restrict__ W1, float* __restrict__ y1){
  __shared__ float sW[D*D];
  for (int i = threadIdx.x; i < D*D; i += blockDim.x) sW[i] = W1[i];
  __syncthreads();
  int n = blockIdx.x*blockDim.x + threadIdx.x;
  if (n >= NN) return;
  const float* em = emb + z[n]*D;
  float h[D];
  #pragma unroll
  for (int j = 0; j < D; j++) h[j] = em[j];
  #pragma unroll
  for (int k = 0; k < D; k++){
    float s = 0.f;
    #pragma unroll
    for (int j = 0; j < D; j++) s += h[j]*sW[j*D+k];
    y1[n*D+k] = s;
  }
}

// conv1 gather + node MLP mid: y2, masks
__global__ void k_conv1_mid(const int* __restrict__ col_src, const float* __restrict__ col_wf,
                            const int* __restrict__ off_col, const int* __restrict__ cnt_col,
                            const float* __restrict__ dinv, const float* __restrict__ y1,
                            const float* __restrict__ b1, const float* __restrict__ Wl1,
                            const float* __restrict__ bl1, const float* __restrict__ W2,
                            float* __restrict__ y2, unsigned* __restrict__ masks){
  __shared__ float sWl1[D*D], sW2[D*D], sb1[D], sbl1[D];
  for (int i = threadIdx.x; i < D*D; i += blockDim.x){ sWl1[i] = Wl1[i]; sW2[i] = W2[i]; }
  if (threadIdx.x < D){ sb1[threadIdx.x] = b1[threadIdx.x]; sbl1[threadIdx.x] = bl1[threadIdx.x]; }
  __syncthreads();
  int t = blockIdx.x*blockDim.x + threadIdx.x;
  int n = t >> 4, k = t & 15;
  if (n >= NN) return;
  int base = off_col[n], cnt = cnt_col[n];
  float acc = 0.f;
  for (int i = 0; i < cnt; i++){
    int r = col_src[base+i];
    float a = col_wf[base+i]*dinv[r];
    acc += a*y1[r*D+k];
  }
  float dv = dinv[n];
  float u1 = dv*acc + dv*dv*y1[n*D+k] + sb1[k];
  float h1 = leakyf(u1);
  float u2 = sbl1[k];
  #pragma unroll
  for (int j = 0; j < D; j++){
    float hj = __shfl(h1, j, 16);
    u2 += hj*sWl1[j*D+k];
  }
  float h2 = leakyf(u2);
  float yo = 0.f;
  #pragma unroll
  for (int j = 0; j < D; j++){
    float hj = __shfl(h2, j, 16);
    yo += hj*sW2[j*D+k];
  }
  y2[n*D+k] = yo;
  unsigned mm = ((u1 >= 0.f) ? (1u<<k) : 0u) | ((u2 >= 0.f) ? (1u<<(16+k)) : 0u);
  mm |= (unsigned)__shfl_xor((int)mm, 8, 16);
  mm |= (unsigned)__shfl_xor((int)mm, 4, 16);
  mm |= (unsigned)__shfl_xor((int)mm, 2, 16);
  mm |= (unsigned)__shfl_xor((int)mm, 1, 16);
  if (k == 0) masks[n] = mm;
}

// conv2 gather + head MLP + energy + backward head -> du3, gdiag
__global__ void k_conv2_out(const int* __restrict__ col_src, const float* __restrict__ col_wf,
                            const int* __restrict__ off_col, const int* __restrict__ cnt_col,
                            const float* __restrict__ dinv, const float* __restrict__ y2,
                            const int* __restrict__ batch,
                            const float* __restrict__ b2, const float* __restrict__ Wl2,
                            const float* __restrict__ bl2, const float* __restrict__ Wl3,
                            const float* __restrict__ bl3,
                            float* __restrict__ Eout, float* __restrict__ du3,
                            float* __restrict__ gdiag){
  __shared__ float sWl2[D*4], sb2[D], sbl2[4], sWl3[4], sbl3s;
  if (threadIdx.x < D*4) sWl2[threadIdx.x] = Wl2[threadIdx.x];
  if (threadIdx.x < D) sb2[threadIdx.x] = b2[threadIdx.x];
  if (threadIdx.x < 4){ sbl2[threadIdx.x] = bl2[threadIdx.x]; sWl3[threadIdx.x] = Wl3[threadIdx.x]; }
  if (threadIdx.x == 0) sbl3s = bl3[0];
  __syncthreads();
  int t = blockIdx.x*blockDim.x + threadIdx.x;
  int n = t >> 4, k = t & 15;
  if (n >= NN) return;
  int base = off_col[n], cnt = cnt_col[n];
  float acc = 0.f;
  for (int i = 0; i < cnt; i++){
    int r = col_src[base+i];
    float a = col_wf[base+i]*dinv[r];
    acc += a*y2[r*D+k];
  }
  float dv = dinv[n];
  float y2k = y2[n*D+k];
  float u3 = dv*acc + dv*dv*y2k + sb2[k];
  float h3 = leakyf(u3);
  float u40 = sbl2[0], u41 = sbl2[1], u42 = sbl2[2], u43 = sbl2[3];
  #pragma unroll
  for (int j = 0; j < D; j++){
    float hj = __shfl(h3, j, 16);
    u40 += hj*sWl2[j*4+0]; u41 += hj*sWl2[j*4+1];
    u42 += hj*sWl2[j*4+2]; u43 += hj*sWl2[j*4+3];
  }
  float h40 = leakyf(u40), h41 = leakyf(u41), h42 = leakyf(u42), h43 = leakyf(u43);
  float u5 = sbl3s + h40*sWl3[0] + h41*sWl3[1] + h42*sWl3[2] + h43*sWl3[3];
  float h5 = leakyf(u5);
  if (k == 0) atomicAdd(&Eout[batch[n]], h5);
  float du5 = dleakyf(u5);
  float d40 = du5*sWl3[0]*dleakyf(u40);
  float d41 = du5*sWl3[1]*dleakyf(u41);
  float d42 = du5*sWl3[2]*dleakyf(u42);
  float d43 = du5*sWl3[3]*dleakyf(u43);
  float g = d40*sWl2[k*4+0] + d41*sWl2[k*4+1] + d42*sWl2[k*4+2] + d43*sWl2[k*4+3];
  float d3 = g*dleakyf(u3);
  du3[n*D+k] = d3;
  float gd = red16(d3*y2k);
  if (k == 0) gdiag[n] = gd;
}

// ---- backward -----------------------------------------------------------
// row gather: gy2[n] = dinv[n]*sum_out w*dinv[c]*du3[c]; gn_row[slot] = du3[c].y2[n]
__global__ void k_bwd2row(const int* __restrict__ row_dst, const float* __restrict__ row_wf,
                          const int* __restrict__ off_row, const int* __restrict__ cnt_row,
                          const float* __restrict__ dinv, const float* __restrict__ y2,
                          const float* __restrict__ du3,
                          float* __restrict__ gy2, float* __restrict__ gn_row){
  int t = blockIdx.x*blockDim.x + threadIdx.x;
  int n = t >> 4, k = t & 15;
  if (n >= NN) return;
  int base = off_row[n], cnt = cnt_row[n];
  float y2k = y2[n*D+k];
  float gacc = 0.f;
  for (int i = 0; i < cnt; i++){
    int c = row_dst[base+i];
    float w = row_wf[base+i];
    float d3 = du3[c*D+k];
    gacc += w*dinv[c]*d3;
    float p = red16(d3*y2k);
    if (k == 0) gn_row[base+i] = p;
  }
  gy2[n*D+k] = dinv[n]*gacc;
}

// node backward mid: (gy2 + selfloop) -> du2 -> du1, gdiag += du1.y1
__global__ void k_node_bwdmid(const float* __restrict__ gy2, const float* __restrict__ du3,
                              const float* __restrict__ y1, const float* __restrict__ dinv,
                              const unsigned* __restrict__ masks,
                              const float* __restrict__ W2, const float* __restrict__ Wl1,
                              float* __restrict__ du1, float* __restrict__ gdiag){
  __shared__ float sW2[D*D], sWl1[D*D];
  for (int i = threadIdx.x; i < D*D; i += blockDim.x){ sW2[i] = W2[i]; sWl1[i] = Wl1[i]; }
  __syncthreads();
  int n = blockIdx.x*blockDim.x + threadIdx.x;
  if (n >= NN) return;
  float dv = dinv[n], d2 = dv*dv;
  unsigned m = masks[n];
  float gy[D];
  #pragma unroll
  for (int k = 0; k < D; k++) gy[k] = gy2[n*D+k] + d2*du3[n*D+k];
  float du2[D];
  #pragma unroll
  for (int k = 0; k < D; k++){
    float g = 0.f;
    #pragma unroll
    for (int j = 0; j < D; j++) g += gy[j]*sW2[k*D+j];
    du2[k] = g * (((m>>(16+k))&1u) ? 1.0f : SLOPE);
  }
  float gd = gdiag[n];
  #pragma unroll
  for (int k = 0; k < D; k++){
    float g = 0.f;
    #pragma unroll
    for (int j = 0; j < D; j++) g += du2[j]*sWl1[k*D+j];
    float d1 = g * (((m>>k)&1u) ? 1.0f : SLOPE);
    du1[n*D+k] = d1;
    gd += d1*y1[n*D+k];
  }
  gdiag[n] = gd;
}

// row gather layer1: gn_row[slot] += du1[c].y1[n]; gdinv[n] = sum_out gn_tot*w*dinv[c]
__global__ void k_bwd1row(const int* __restrict__ row_dst, const float* __restrict__ row_wf,
                          const int* __restrict__ off_row, const int* __restrict__ cnt_row,
                          const float* __restrict__ dinv, const float* __restrict__ y1,
                          const float* __restrict__ du1,
                          float* __restrict__ gn_row, float* __restrict__ gdinv){
  int t = blockIdx.x*blockDim.x + threadIdx.x;
  int n = t >> 4, k = t & 15;
  if (n >= NN) return;
  int base = off_row[n], cnt = cnt_row[n];
  float y1k = y1[n*D+k];
  float gdr = 0.f;
  for (int i = 0; i < cnt; i++){
    int c = row_dst[base+i];
    float d1 = du1[c*D+k];
    float p = red16(d1*y1k);
    if (k == 0){
      float g = gn_row[base+i] + p;
      gn_row[base+i] = g;
      gdr += g*row_wf[base+i]*dinv[c];
    }
  }
  if (k == 0) gdinv[n] = gdr;
}

// col gather: gdinv += sum_in gn*w*dinv[r]; gdeg = -0.5*dinv^3*(gdinv + 2*dinv*gdiag)
__global__ void k_gdeg(const int* __restrict__ col_src, const float* __restrict__ col_wf,
                       const int* __restrict__ col_rp,
                       const int* __restrict__ off_col, const int* __restrict__ cnt_col,
                       const float* __restrict__ dinv, const float* __restrict__ gn_row,
                       const float* __restrict__ gdinv, const float* __restrict__ gdiag,
                       float* __restrict__ gdeg){
  int t = blockIdx.x*blockDim.x + threadIdx.x;
  int n = t >> 4, k = t & 15;
  if (n >= NN) return;
  int base = off_col[n], cnt = cnt_col[n];
  float gc = 0.f;
  for (int i = k; i < cnt; i += 16){
    int r = col_src[base+i];
    gc += gn_row[col_rp[base+i]]*col_wf[base+i]*dinv[r];
  }
  gc = red16(gc);
  if (k == 0){
    float dv = dinv[n];
    float g = gdinv[n] + gc + 2.0f*dv*gdiag[n];
    gdeg[n] = -0.5f*dv*dv*dv*g;
  }
}

// force gather: both incidence directions, direct store
__global__ void k_force(const int* __restrict__ row_dst, const float* __restrict__ row_wf,
                        const int* __restrict__ off_row, const int* __restrict__ cnt_row,
                        const int* __restrict__ col_src, const float* __restrict__ col_wf,
                        const int* __restrict__ col_rp,
                        const int* __restrict__ off_col, const int* __restrict__ cnt_col,
                        const float* __restrict__ pos, const float* __restrict__ dinv,
                        const float* __restrict__ gn_row, const float* __restrict__ gdeg,
                        float* __restrict__ F){
  int t = blockIdx.x*blockDim.x + threadIdx.x;
  int n = t >> 4, k = t & 15;
  if (n >= NN) return;
  float dvn = dinv[n], gdn = gdeg[n];
  float px = pos[3*n+0], py = pos[3*n+1], pz = pos[3*n+2];
  float fx = 0.f, fy = 0.f, fz = 0.f;
  int base = off_row[n], cnt = cnt_row[n];
  for (int i = k; i < cnt; i += 16){
    int c = row_dst[base+i];
    float w = row_wf[base+i];
    float coef = (gn_row[base+i]*dvn*dinv[c] + gdeg[c]) / w;
    float dx = px - pos[3*c+0], dy = py - pos[3*c+1], dz = pz - pos[3*c+2];
    fx -= coef*dx; fy -= coef*dy; fz -= coef*dz;
  }
  base = off_col[n]; cnt = cnt_col[n];
  for (int i = k; i < cnt; i += 16){
    int r = col_src[base+i];
    float w = col_wf[base+i];
    float coef = (gn_row[col_rp[base+i]]*dinv[r]*dvn + gdn) / w;
    float dx = pos[3*r+0] - px, dy = pos[3*r+1] - py, dz = pos[3*r+2] - pz;
    fx += coef*dx; fy += coef*dy; fz += coef*dz;
  }
  fx = red16(fx); fy = red16(fy); fz = red16(fz);
  if (k == 0){ F[3*n+0] = fx; F[3*n+1] = fy; F[3*n+2] = fz; }
}

extern "C" void kernel_launch(void* const* d_in, const int* in_sizes, int n_in,
                              void* d_out, int out_size, void* d_ws, size_t ws_size,
                              hipStream_t stream){
  const float* pos = (const float*)d_in[0];
  const float* emb = (const float*)d_in[1];
  const float* W1  = (const float*)d_in[2];
  const float* b1  = (const float*)d_in[3];
  const float* Wl1 = (const float*)d_in[4];
  const float* bl1 = (const float*)d_in[5];
  const float* W2  = (const float*)d_in[6];
  const float* b2  = (const float*)d_in[7];
  const float* Wl2 = (const float*)d_in[8];
  const float* bl2 = (const float*)d_in[9];
  const float* Wl3 = (const float*)d_in[10];
  const float* bl3 = (const float*)d_in[11];
  const int* z     = (const int*)d_in[12];
  const int* ei    = (const int*)d_in[13];
  const int* batch = (const int*)d_in[14];

  // workspace layout (4-byte words): 91N + 1024 + 6E  (~113 MB)
  char* base = (char*)d_ws;
  size_t o = 0;
  auto alloc = [&](size_t words){ void* p = base + o*4; o += words; return p; };
  int*   cnt_row = (int*)alloc(NN);
  int*   cnt_col = (int*)alloc(NN);
  int*   off_row = (int*)alloc(NN);
  int*   off_col = (int*)alloc(NN);
  int*   cur_row = (int*)alloc(NN);
  int*   cur_col = (int*)alloc(NN);
  int*   bsum    = (int*)alloc(1024);
  float* dinv    = (float*)alloc(NN);
  float* gdiag   = (float*)alloc(NN);
  float* gdeg    = (float*)alloc(NN);
  float* gdinv   = (float*)alloc(NN);
  unsigned* masks = (unsigned*)alloc(NN);
  float* y1      = (float*)alloc(16*NN);
  float* y2      = (float*)alloc(16*NN);
  float* du3     = (float*)alloc(16*NN);
  float* gy2     = (float*)alloc(16*NN);
  float* du1     = (float*)alloc(16*NN);
  int*   row_dst = (int*)alloc(NE);
  float* row_wf  = (float*)alloc(NE);
  int*   col_src = (int*)alloc(NE);
  int*   col_rp  = (int*)alloc(NE);
  float* col_wf  = (float*)alloc(NE);
  float* gn_row  = (float*)alloc(NE);

  float* Eout = (float*)d_out;
  float* F = Eout + NG;

  int nbN   = (NN + BT - 1)/BT;           // 391
  int nbE   = (NE + BT - 1)/BT;
  int nbN16 = (NN*16 + BT - 1)/BT;        // 6250

  // zero counters + energy output
  k_fill<<<(2*NN + BT - 1)/BT, BT, 0, stream>>>((float*)cnt_row, 2*NN, 0.0f);
  k_fill<<<(NG + BT - 1)/BT, BT, 0, stream>>>(Eout, NG, 0.0f);

  // CSR build
  k_count<<<nbE, BT, 0, stream>>>(ei, cnt_row, cnt_col);
  k_blocksum<<<dim3(nbN,2), BT, 0, stream>>>(cnt_row, cnt_col, bsum);
  k_scan_bsum<<<dim3(1,2), 512, 0, stream>>>(bsum, nbN);
  k_offsets<<<dim3(nbN,2), BT, 0, stream>>>(cnt_row, cnt_col, bsum,
                                            off_row, off_col, cur_row, cur_col);
  k_place<<<nbE, BT, 0, stream>>>(ei, pos, cur_row, cur_col,
                                  row_dst, row_wf, col_src, col_rp, col_wf);

  // forward
  k_dinv<<<nbN16, BT, 0, stream>>>(col_wf, off_col, cnt_col, dinv);
  k_y1<<<nbN, BT, 0, stream>>>(emb, z, W1, y1);
  k_conv1_mid<<<nbN16, BT, 0, stream>>>(col_src, col_wf, off_col, cnt_col, dinv, y1,
                                        b1, Wl1, bl1, W2, y2, masks);
  k_conv2_out<<<nbN16, BT, 0, stream>>>(col_src, col_wf, off_col, cnt_col, dinv, y2,
                                        batch, b2, Wl2, bl2, Wl3, bl3, Eout, du3, gdiag);

  // backward
  k_bwd2row<<<nbN16, BT, 0, stream>>>(row_dst, row_wf, off_row, cnt_row, dinv, y2, du3,
                                      gy2, gn_row);
  k_node_bwdmid<<<nbN, BT, 0, stream>>>(gy2, du3, y1, dinv, masks, W2, Wl1, du1, gdiag);
  k_bwd1row<<<nbN16, BT, 0, stream>>>(row_dst, row_wf, off_row, cnt_row, dinv, y1, du1,
                                      gn_row, gdinv);
  k_gdeg<<<nbN16, BT, 0, stream>>>(col_src, col_wf, col_rp, off_col, cnt_col, dinv,
                                   gn_row, gdinv, gdiag, gdeg);
  k_force<<<nbN16, BT, 0, stream>>>(row_dst, row_wf, off_row, cnt_row,
                                    col_src, col_wf, col_rp, off_col, cnt_col,
                                    pos, dinv, gn_row, gdeg, F);
}

// Round 3
// 1357.882 us; speedup vs baseline: 1.7789x; 1.0934x over previous
//
#include <hip/hip_runtime.h>
#include <math.h>

#define NN 100000
#define NE 3200000
#define NG 512
#define D 16
#define SLOPE 0.01f
#define BT 256

struct Row8  { int dst; float w; };            // 8B, one scattered store
struct Col12 { int src; int rp; float w; };    // 12B, one scattered store

__device__ __forceinline__ float leakyf(float x){ return x >= 0.0f ? x : SLOPE*x; }
__device__ __forceinline__ float dleakyf(float x){ return x >= 0.0f ? 1.0f : SLOPE; }

__device__ __forceinline__ float red16(float v){
  v += __shfl_xor(v, 8, 16);
  v += __shfl_xor(v, 4, 16);
  v += __shfl_xor(v, 2, 16);
  v += __shfl_xor(v, 1, 16);
  return v;
}

__global__ void k_fill(float* __restrict__ p, int n, float v){
  int i = blockIdx.x*blockDim.x + threadIdx.x;
  if (i < n) p[i] = v;
}

// ---- CSR build ----------------------------------------------------------
__global__ void k_count(const int* __restrict__ ei, int* __restrict__ cnt_row,
                        int* __restrict__ cnt_col){
  int e = blockIdx.x*blockDim.x + threadIdx.x;
  if (e >= NE) return;
  atomicAdd(&cnt_row[ei[e]], 1);
  atomicAdd(&cnt_col[ei[NE+e]], 1);
}

__global__ void k_blocksum(const int* __restrict__ cnt_row, const int* __restrict__ cnt_col,
                           int* __restrict__ bsum){
  const int* src = blockIdx.y ? cnt_col : cnt_row;
  __shared__ int s[BT];
  int i = blockIdx.x*BT + threadIdx.x;
  s[threadIdx.x] = (i < NN) ? src[i] : 0;
  __syncthreads();
  for (int off = BT/2; off > 0; off >>= 1){
    if (threadIdx.x < off) s[threadIdx.x] += s[threadIdx.x+off];
    __syncthreads();
  }
  if (threadIdx.x == 0) bsum[blockIdx.y*512 + blockIdx.x] = s[0];
}

__global__ void k_scan_bsum(int* __restrict__ bsum, int nb){
  int* b = bsum + blockIdx.y*512;
  __shared__ int s0[512], s1[512];
  int tid = threadIdx.x;
  int v = (tid < nb) ? b[tid] : 0;
  s0[tid] = v; __syncthreads();
  int rd = 0;
  for (int off = 1; off < 512; off <<= 1){
    int x = rd ? s1[tid] : s0[tid];
    if (tid >= off) x += rd ? s1[tid-off] : s0[tid-off];
    if (rd) s0[tid] = x; else s1[tid] = x;
    __syncthreads();
    rd ^= 1;
  }
  int incl = rd ? s1[tid] : s0[tid];
  if (tid < nb) b[tid] = incl - v;
}

__global__ void k_offsets(const int* __restrict__ cnt_row, const int* __restrict__ cnt_col,
                          const int* __restrict__ bsum,
                          int* __restrict__ off_row, int* __restrict__ off_col,
                          int* __restrict__ cur_row, int* __restrict__ cur_col){
  const int* src  = blockIdx.y ? cnt_col : cnt_row;
  int* offd = blockIdx.y ? off_col : off_row;
  int* curd = blockIdx.y ? cur_col : cur_row;
  __shared__ int s0[BT], s1[BT];
  int tid = threadIdx.x;
  int i = blockIdx.x*BT + tid;
  int v = (i < NN) ? src[i] : 0;
  s0[tid] = v; __syncthreads();
  int rd = 0;
  for (int off = 1; off < BT; off <<= 1){
    int x = rd ? s1[tid] : s0[tid];
    if (tid >= off) x += rd ? s1[tid-off] : s0[tid-off];
    if (rd) s0[tid] = x; else s1[tid] = x;
    __syncthreads();
    rd ^= 1;
  }
  int incl = rd ? s1[tid] : s0[tid];
  if (i < NN){
    int o = bsum[blockIdx.y*512 + blockIdx.x] + incl - v;
    offd[i] = o; curd[i] = o;
  }
}

__global__ void k_place(const int* __restrict__ ei, const float* __restrict__ pos,
                        int* __restrict__ cur_row, int* __restrict__ cur_col,
                        Row8* __restrict__ row8, Col12* __restrict__ col12){
  int e = blockIdx.x*blockDim.x + threadIdx.x;
  if (e >= NE) return;
  int r = ei[e], c = ei[NE+e];
  float dx = pos[3*r+0]-pos[3*c+0];
  float dy = pos[3*r+1]-pos[3*c+1];
  float dz = pos[3*r+2]-pos[3*c+2];
  float w = sqrtf(dx*dx+dy*dy+dz*dz);
  int p = atomicAdd(&cur_row[r], 1);
  int q = atomicAdd(&cur_col[c], 1);
  ((int2*)row8)[p] = make_int2(c, __float_as_int(w));
  Col12 cc; cc.src = r; cc.rp = p; cc.w = w;
  col12[q] = cc;
}

// ---- forward ------------------------------------------------------------
// dinv + ys1 = dinv * (emb[z] @ W1)
__global__ void k_dinv_y1(const Col12* __restrict__ col, const int* __restrict__ off_col,
                          const int* __restrict__ cnt_col,
                          const float* __restrict__ emb, const int* __restrict__ z,
                          const float* __restrict__ W1,
                          float* __restrict__ dinv, float* __restrict__ ys1){
  __shared__ float sW[D*D];
  for (int i = threadIdx.x; i < D*D; i += blockDim.x) sW[i] = W1[i];
  __syncthreads();
  int t = blockIdx.x*blockDim.x + threadIdx.x;
  int n = t >> 4, k = t & 15;
  if (n >= NN) return;
  int base = off_col[n], cnt = cnt_col[n];
  float s = 0.f;
  for (int i = k; i < cnt; i += 16) s += col[base+i].w;
  s = red16(s);
  float dv = 1.0f / sqrtf(1.0f + s);
  if (k == 0) dinv[n] = dv;
  float h = emb[z[n]*D + k];
  float acc = 0.f;
  #pragma unroll
  for (int j = 0; j < D; j++) acc += __shfl(h, j, 16)*sW[j*D+k];
  ys1[n*D+k] = dv*acc;
}

// conv1 gather (scaled) + MLP mid: ys2, masks
__global__ void k_conv1_mid(const Col12* __restrict__ col, const int* __restrict__ off_col,
                            const int* __restrict__ cnt_col,
                            const float* __restrict__ dinv, const float* __restrict__ ys1,
                            const float* __restrict__ b1, const float* __restrict__ Wl1,
                            const float* __restrict__ bl1, const float* __restrict__ W2,
                            float* __restrict__ ys2, unsigned* __restrict__ masks){
  __shared__ float sWl1[D*D], sW2[D*D], sb1[D], sbl1[D];
  for (int i = threadIdx.x; i < D*D; i += blockDim.x){ sWl1[i] = Wl1[i]; sW2[i] = W2[i]; }
  if (threadIdx.x < D){ sb1[threadIdx.x] = b1[threadIdx.x]; sbl1[threadIdx.x] = bl1[threadIdx.x]; }
  __syncthreads();
  int t = blockIdx.x*blockDim.x + threadIdx.x;
  int n = t >> 4, k = t & 15;
  if (n >= NN) return;
  int base = off_col[n], cnt = cnt_col[n];
  float acc = 0.f;
  for (int i = 0; i < cnt; i++){
    Col12 cc = col[base+i];
    acc += cc.w * ys1[cc.src*D+k];
  }
  float dv = dinv[n];
  float u1 = dv*(acc + ys1[n*D+k]) + sb1[k];
  float h1 = leakyf(u1);
  float u2 = sbl1[k];
  #pragma unroll
  for (int j = 0; j < D; j++) u2 += __shfl(h1, j, 16)*sWl1[j*D+k];
  float h2 = leakyf(u2);
  float yo = 0.f;
  #pragma unroll
  for (int j = 0; j < D; j++) yo += __shfl(h2, j, 16)*sW2[j*D+k];
  ys2[n*D+k] = dv*yo;
  unsigned mm = ((u1 >= 0.f) ? (1u<<k) : 0u) | ((u2 >= 0.f) ? (1u<<(16+k)) : 0u);
  mm |= (unsigned)__shfl_xor((int)mm, 8, 16);
  mm |= (unsigned)__shfl_xor((int)mm, 4, 16);
  mm |= (unsigned)__shfl_xor((int)mm, 2, 16);
  mm |= (unsigned)__shfl_xor((int)mm, 1, 16);
  if (k == 0) masks[n] = mm;
}

// conv2 gather (scaled) + head + energy + head backward: ds3, gdiag_s
__global__ void k_conv2_out(const Col12* __restrict__ col, const int* __restrict__ off_col,
                            const int* __restrict__ cnt_col,
                            const float* __restrict__ dinv, const float* __restrict__ ys2,
                            const int* __restrict__ batch,
                            const float* __restrict__ b2, const float* __restrict__ Wl2,
                            const float* __restrict__ bl2, const float* __restrict__ Wl3,
                            const float* __restrict__ bl3,
                            float* __restrict__ Eout, float* __restrict__ ds3,
                            float* __restrict__ gdiag){
  __shared__ float sWl2[D*4], sb2[D], sbl2[4], sWl3[4], sbl3s;
  if (threadIdx.x < D*4) sWl2[threadIdx.x] = Wl2[threadIdx.x];
  if (threadIdx.x < D) sb2[threadIdx.x] = b2[threadIdx.x];
  if (threadIdx.x < 4){ sbl2[threadIdx.x] = bl2[threadIdx.x]; sWl3[threadIdx.x] = Wl3[threadIdx.x]; }
  if (threadIdx.x == 0) sbl3s = bl3[0];
  __syncthreads();
  int t = blockIdx.x*blockDim.x + threadIdx.x;
  int n = t >> 4, k = t & 15;
  if (n >= NN) return;
  int base = off_col[n], cnt = cnt_col[n];
  float acc = 0.f;
  for (int i = 0; i < cnt; i++){
    Col12 cc = col[base+i];
    acc += cc.w * ys2[cc.src*D+k];
  }
  float dv = dinv[n];
  float ysk = ys2[n*D+k];
  float u3 = dv*(acc + ysk) + sb2[k];
  float h3 = leakyf(u3);
  float u40 = sbl2[0], u41 = sbl2[1], u42 = sbl2[2], u43 = sbl2[3];
  #pragma unroll
  for (int j = 0; j < D; j++){
    float hj = __shfl(h3, j, 16);
    u40 += hj*sWl2[j*4+0]; u41 += hj*sWl2[j*4+1];
    u42 += hj*sWl2[j*4+2]; u43 += hj*sWl2[j*4+3];
  }
  float h40 = leakyf(u40), h41 = leakyf(u41), h42 = leakyf(u42), h43 = leakyf(u43);
  float u5 = sbl3s + h40*sWl3[0] + h41*sWl3[1] + h42*sWl3[2] + h43*sWl3[3];
  float h5 = leakyf(u5);
  if (k == 0) atomicAdd(&Eout[batch[n]], h5);
  float du5 = dleakyf(u5);
  float d40 = du5*sWl3[0]*dleakyf(u40);
  float d41 = du5*sWl3[1]*dleakyf(u41);
  float d42 = du5*sWl3[2]*dleakyf(u42);
  float d43 = du5*sWl3[3]*dleakyf(u43);
  float g = d40*sWl2[k*4+0] + d41*sWl2[k*4+1] + d42*sWl2[k*4+2] + d43*sWl2[k*4+3];
  float d3 = g*dleakyf(u3);
  ds3[n*D+k] = dv*d3;
  float gd = red16(d3*ysk);          // gdiag_s = dv * (du3 . y2)
  if (k == 0) gdiag[n] = gd;
}

// ---- backward -----------------------------------------------------------
// row pass 2: gy2[n] = dv*sum_out w*ds3[c]; gn_row[slot] = gns2 = ds3[c].ys2[n]
__global__ void k_bwd2row(const Row8* __restrict__ row8, const int* __restrict__ off_row,
                          const int* __restrict__ cnt_row,
                          const float* __restrict__ dinv, const float* __restrict__ ys2,
                          const float* __restrict__ ds3,
                          float* __restrict__ gy2, float* __restrict__ gn_row){
  int t = blockIdx.x*blockDim.x + threadIdx.x;
  int n = t >> 4, k = t & 15;
  if (n >= NN) return;
  int base = off_row[n], cnt = cnt_row[n];
  float ysk = ys2[n*D+k];
  float gacc = 0.f;
  for (int i = 0; i < cnt; i++){
    Row8 rr = row8[base+i];
    float dval = ds3[rr.dst*D+k];
    gacc += rr.w*dval;
    float p = red16(dval*ysk);
    if (k == 0) gn_row[base+i] = p;
  }
  gy2[n*D+k] = dinv[n]*gacc;
}

// node backward mid (16-lane): du1, ds1, gdiag_s += du1.ys1
__global__ void k_node_bwdmid(const float* __restrict__ gy2, const float* __restrict__ ds3,
                              const float* __restrict__ ys1, const float* __restrict__ dinv,
                              const unsigned* __restrict__ masks,
                              const float* __restrict__ W2, const float* __restrict__ Wl1,
                              float* __restrict__ ds1, float* __restrict__ gdiag){
  __shared__ float sW2[D*D], sWl1[D*D];
  for (int i = threadIdx.x; i < D*D; i += blockDim.x){ sW2[i] = W2[i]; sWl1[i] = Wl1[i]; }
  __syncthreads();
  int t = blockIdx.x*blockDim.x + threadIdx.x;
  int n = t >> 4, k = t & 15;
  if (n >= NN) return;
  float dv = dinv[n];
  unsigned m = masks[n];
  float gy = gy2[n*D+k] + dv*ds3[n*D+k];   // d2*du3 = dv*ds3
  float du2 = 0.f;
  #pragma unroll
  for (int j = 0; j < D; j++) du2 += __shfl(gy, j, 16)*sW2[k*D+j];
  du2 *= ((m>>(16+k))&1u) ? 1.0f : SLOPE;
  float du1 = 0.f;
  #pragma unroll
  for (int j = 0; j < D; j++) du1 += __shfl(du2, j, 16)*sWl1[k*D+j];
  du1 *= ((m>>k)&1u) ? 1.0f : SLOPE;
  float gd = red16(du1*ys1[n*D+k]);        // adds dv*(du1 . y1)
  if (k == 0) gdiag[n] += gd;
  ds1[n*D+k] = dv*du1;
}

// row pass 1: gn_row[slot] += ds1[c].ys1[n]; gdinv_row[n] = sum_out gns*w (raw)
__global__ void k_bwd1row(const Row8* __restrict__ row8, const int* __restrict__ off_row,
                          const int* __restrict__ cnt_row,
                          const float* __restrict__ ys1, const float* __restrict__ ds1,
                          float* __restrict__ gn_row, float* __restrict__ gdinv_row){
  int t = blockIdx.x*blockDim.x + threadIdx.x;
  int n = t >> 4, k = t & 15;
  if (n >= NN) return;
  int base = off_row[n], cnt = cnt_row[n];
  float ysk = ys1[n*D+k];
  float gdr = 0.f;
  for (int i = 0; i < cnt; i++){
    Row8 rr = row8[base+i];
    float dval = ds1[rr.dst*D+k];
    float p = red16(dval*ysk);
    float g = gn_row[base+i] + p;        // broadcast read
    if (k == 0) gn_row[base+i] = g;
    gdr += g*rr.w;
  }
  if (k == 0) gdinv_row[n] = gdr;
}

// col pass: gns_col copy (contiguous), gdeg, packed node table (pos, gdeg)
__global__ void k_gdeg(const Col12* __restrict__ col, const int* __restrict__ off_col,
                       const int* __restrict__ cnt_col,
                       const float* __restrict__ gn_row, const float* __restrict__ gdinv_row,
                       const float* __restrict__ gdiag, const float* __restrict__ dinv,
                       const float* __restrict__ pos,
                       float* __restrict__ gns_col, float4* __restrict__ pn4){
  int t = blockIdx.x*blockDim.x + threadIdx.x;
  int n = t >> 4, k = t & 15;
  if (n >= NN) return;
  int base = off_col[n], cnt = cnt_col[n];
  float gc = 0.f;
  for (int i = k; i < cnt; i += 16){
    Col12 cc = col[base+i];
    float g = gn_row[cc.rp];
    gc += g*cc.w;
    gns_col[base+i] = g;
  }
  gc = red16(gc);
  if (k == 0){
    float dv = dinv[n];
    float arg = (gdinv_row[n] + gc)/dv + 2.0f*gdiag[n];  // gdiag holds dv*gdiag_true
    float gd = -0.5f*dv*dv*dv*arg;
    pn4[n] = make_float4(pos[3*n+0], pos[3*n+1], pos[3*n+2], gd);
  }
}

// force gather: coef = (gns + gdeg[col-node])/w, both directions
__global__ void k_force(const Row8* __restrict__ row8, const int* __restrict__ off_row,
                        const int* __restrict__ cnt_row,
                        const Col12* __restrict__ col, const int* __restrict__ off_col,
                        const int* __restrict__ cnt_col,
                        const float* __restrict__ gn_row, const float* __restrict__ gns_col,
                        const float4* __restrict__ pn4, float* __restrict__ F){
  int t = blockIdx.x*blockDim.x + threadIdx.x;
  int n = t >> 4, k = t & 15;
  if (n >= NN) return;
  float4 pn = pn4[n];
  float fx = 0.f, fy = 0.f, fz = 0.f;
  int base = off_row[n], cnt = cnt_row[n];
  for (int i = k; i < cnt; i += 16){
    Row8 rr = row8[base+i];
    float g = gn_row[base+i];
    float4 pc = pn4[rr.dst];
    float coef = (g + pc.w)/rr.w;
    fx -= coef*(pn.x-pc.x); fy -= coef*(pn.y-pc.y); fz -= coef*(pn.z-pc.z);
  }
  base = off_col[n]; cnt = cnt_col[n];
  for (int i = k; i < cnt; i += 16){
    Col12 cc = col[base+i];
    float g = gns_col[base+i];
    float4 pr = pn4[cc.src];
    float coef = (g + pn.w)/cc.w;
    fx += coef*(pr.x-pn.x); fy += coef*(pr.y-pn.y); fz += coef*(pr.z-pn.z);
  }
  fx = red16(fx); fy = red16(fy); fz = red16(fz);
  if (k == 0){ F[3*n+0] = fx; F[3*n+1] = fy; F[3*n+2] = fz; }
}

extern "C" void kernel_launch(void* const* d_in, const int* in_sizes, int n_in,
                              void* d_out, int out_size, void* d_ws, size_t ws_size,
                              hipStream_t stream){
  const float* pos = (const float*)d_in[0];
  const float* emb = (const float*)d_in[1];
  const float* W1  = (const float*)d_in[2];
  const float* b1  = (const float*)d_in[3];
  const float* Wl1 = (const float*)d_in[4];
  const float* bl1 = (const float*)d_in[5];
  const float* W2  = (const float*)d_in[6];
  const float* b2  = (const float*)d_in[7];
  const float* Wl2 = (const float*)d_in[8];
  const float* bl2 = (const float*)d_in[9];
  const float* Wl3 = (const float*)d_in[10];
  const float* bl3 = (const float*)d_in[11];
  const int* z     = (const int*)d_in[12];
  const int* ei    = (const int*)d_in[13];
  const int* batch = (const int*)d_in[14];

  // workspace: 90N + 6E words (+pads) ~= 112.9 MB (<= round-2 footprint)
  char* base = (char*)d_ws;
  size_t o = 0;
  auto alloc = [&](size_t words){ o = (o + 3) & ~(size_t)3; void* p = base + o*4; o += words; return p; };
  int*   cnt_row   = (int*)alloc(NN);
  int*   cnt_col   = (int*)alloc(NN);
  int*   off_row   = (int*)alloc(NN);
  int*   off_col   = (int*)alloc(NN);
  int*   cur_row   = (int*)alloc(NN);
  int*   cur_col   = (int*)alloc(NN);
  int*   bsum      = (int*)alloc(1024);
  float* dinv      = (float*)alloc(NN);
  float* gdiag     = (float*)alloc(NN);
  float* gdinv_row = (float*)alloc(NN);
  unsigned* masks  = (unsigned*)alloc(NN);
  float* ys1       = (float*)alloc(16*NN);
  float* ys2       = (float*)alloc(16*NN);
  float* ds3       = (float*)alloc(16*NN);
  float* gy2       = (float*)alloc(16*NN);
  float* ds1       = (float*)alloc(16*NN);
  Row8*  row8      = (Row8*)alloc(2*(size_t)NE);
  Col12* col12     = (Col12*)alloc(3*(size_t)NE);
  float* gn_row    = (float*)alloc(NE);
  // aliases (lifetimes disjoint): gns_col over ys1+ys2 (E == 32N), pn4 over ds3
  float*  gns_col = ys1;
  float4* pn4     = (float4*)ds3;

  float* Eout = (float*)d_out;
  float* F = Eout + NG;

  int nbN   = (NN + BT - 1)/BT;        // 391
  int nbE   = (NE + BT - 1)/BT;
  int nbN16 = (NN*16 + BT - 1)/BT;     // 6250

  k_fill<<<(2*NN + BT - 1)/BT, BT, 0, stream>>>((float*)cnt_row, 2*NN, 0.0f);
  k_fill<<<(NG + BT - 1)/BT, BT, 0, stream>>>(Eout, NG, 0.0f);

  // CSR build
  k_count<<<nbE, BT, 0, stream>>>(ei, cnt_row, cnt_col);
  k_blocksum<<<dim3(nbN,2), BT, 0, stream>>>(cnt_row, cnt_col, bsum);
  k_scan_bsum<<<dim3(1,2), 512, 0, stream>>>(bsum, nbN);
  k_offsets<<<dim3(nbN,2), BT, 0, stream>>>(cnt_row, cnt_col, bsum,
                                            off_row, off_col, cur_row, cur_col);
  k_place<<<nbE, BT, 0, stream>>>(ei, pos, cur_row, cur_col, row8, col12);

  // forward
  k_dinv_y1<<<nbN16, BT, 0, stream>>>(col12, off_col, cnt_col, emb, z, W1, dinv, ys1);
  k_conv1_mid<<<nbN16, BT, 0, stream>>>(col12, off_col, cnt_col, dinv, ys1,
                                        b1, Wl1, bl1, W2, ys2, masks);
  k_conv2_out<<<nbN16, BT, 0, stream>>>(col12, off_col, cnt_col, dinv, ys2,
                                        batch, b2, Wl2, bl2, Wl3, bl3, Eout, ds3, gdiag);

  // backward
  k_bwd2row<<<nbN16, BT, 0, stream>>>(row8, off_row, cnt_row, dinv, ys2, ds3, gy2, gn_row);
  k_node_bwdmid<<<nbN16, BT, 0, stream>>>(gy2, ds3, ys1, dinv, masks, W2, Wl1, ds1, gdiag);
  k_bwd1row<<<nbN16, BT, 0, stream>>>(row8, off_row, cnt_row, ys1, ds1, gn_row, gdinv_row);
  k_gdeg<<<nbN16, BT, 0, stream>>>(col12, off_col, cnt_col, gn_row, gdinv_row, gdiag, dinv,
                                   pos, gns_col, pn4);
  k_force<<<nbN16, BT, 0, stream>>>(row8, off_row, cnt_row, col12, off_col, cnt_col,
                                    gn_row, gns_col, pn4, F);
}

// Round 4
// 1336.675 us; speedup vs baseline: 1.8071x; 1.0159x over previous
//
#include <hip/hip_runtime.h>
#include <math.h>

#define NN 100000
#define NE 3200000
#define NG 512
#define D 16
#define SLOPE 0.01f
#define BT 256

__device__ __forceinline__ float leakyf(float x){ return x >= 0.0f ? x : SLOPE*x; }
__device__ __forceinline__ float dleakyf(float x){ return x >= 0.0f ? 1.0f : SLOPE; }

__device__ __forceinline__ float red16(float v){
  v += __shfl_xor(v, 8, 16);
  v += __shfl_xor(v, 4, 16);
  v += __shfl_xor(v, 2, 16);
  v += __shfl_xor(v, 1, 16);
  return v;
}

__global__ void k_fill(float* __restrict__ p, int n, float v){
  int i = blockIdx.x*blockDim.x + threadIdx.x;
  if (i < n) p[i] = v;
}

// ---- CSR build ----------------------------------------------------------
__global__ void k_count(const int* __restrict__ ei, int* __restrict__ cnt_row,
                        int* __restrict__ cnt_col){
  int e = blockIdx.x*blockDim.x + threadIdx.x;
  if (e >= NE) return;
  atomicAdd(&cnt_row[ei[e]], 1);
  atomicAdd(&cnt_col[ei[NE+e]], 1);
}

__global__ void k_blocksum(const int* __restrict__ cnt_row, const int* __restrict__ cnt_col,
                           int* __restrict__ bsum){
  const int* src = blockIdx.y ? cnt_col : cnt_row;
  __shared__ int s[BT];
  int i = blockIdx.x*BT + threadIdx.x;
  s[threadIdx.x] = (i < NN) ? src[i] : 0;
  __syncthreads();
  for (int off = BT/2; off > 0; off >>= 1){
    if (threadIdx.x < off) s[threadIdx.x] += s[threadIdx.x+off];
    __syncthreads();
  }
  if (threadIdx.x == 0) bsum[blockIdx.y*512 + blockIdx.x] = s[0];
}

__global__ void k_scan_bsum(int* __restrict__ bsum, int nb){
  int* b = bsum + blockIdx.y*512;
  __shared__ int s0[512], s1[512];
  int tid = threadIdx.x;
  int v = (tid < nb) ? b[tid] : 0;
  s0[tid] = v; __syncthreads();
  int rd = 0;
  for (int off = 1; off < 512; off <<= 1){
    int x = rd ? s1[tid] : s0[tid];
    if (tid >= off) x += rd ? s1[tid-off] : s0[tid-off];
    if (rd) s0[tid] = x; else s1[tid] = x;
    __syncthreads();
    rd ^= 1;
  }
  int incl = rd ? s1[tid] : s0[tid];
  if (tid < nb) b[tid] = incl - v;
}

__global__ void k_offsets(const int* __restrict__ cnt_row, const int* __restrict__ cnt_col,
                          const int* __restrict__ bsum,
                          int* __restrict__ off_row, int* __restrict__ off_col,
                          int* __restrict__ cur_row, int* __restrict__ cur_col){
  const int* src  = blockIdx.y ? cnt_col : cnt_row;
  int* offd = blockIdx.y ? off_col : off_row;
  int* curd = blockIdx.y ? cur_col : cur_row;
  __shared__ int s0[BT], s1[BT];
  int tid = threadIdx.x;
  int i = blockIdx.x*BT + tid;
  int v = (i < NN) ? src[i] : 0;
  s0[tid] = v; __syncthreads();
  int rd = 0;
  for (int off = 1; off < BT; off <<= 1){
    int x = rd ? s1[tid] : s0[tid];
    if (tid >= off) x += rd ? s1[tid-off] : s0[tid-off];
    if (rd) s0[tid] = x; else s1[tid] = x;
    __syncthreads();
    rd ^= 1;
  }
  int incl = rd ? s1[tid] : s0[tid];
  if (i < NN){
    int o = bsum[blockIdx.y*512 + blockIdx.x] + incl - v;
    offd[i] = o; curd[i] = o;
  }
}

// SoA scattered 4B stores (measured faster than wide AoS scatters, r2 vs r3)
__global__ void k_place(const int* __restrict__ ei, const float* __restrict__ pos,
                        int* __restrict__ cur_row, int* __restrict__ cur_col,
                        int* __restrict__ row_dst, float* __restrict__ row_w,
                        int* __restrict__ col_src, int* __restrict__ col_rp,
                        float* __restrict__ col_w){
  int e = blockIdx.x*blockDim.x + threadIdx.x;
  if (e >= NE) return;
  int r = ei[e], c = ei[NE+e];
  float dx = pos[3*r+0]-pos[3*c+0];
  float dy = pos[3*r+1]-pos[3*c+1];
  float dz = pos[3*r+2]-pos[3*c+2];
  float w = sqrtf(dx*dx+dy*dy+dz*dz);
  int p = atomicAdd(&cur_row[r], 1);
  int q = atomicAdd(&cur_col[c], 1);
  row_dst[p] = c; row_w[p] = w;
  col_src[q] = r; col_rp[q] = p; col_w[q] = w;
}

// ---- forward ------------------------------------------------------------
__global__ void k_dinv_y1(const float* __restrict__ col_w, const int* __restrict__ off_col,
                          const int* __restrict__ cnt_col,
                          const float* __restrict__ emb, const int* __restrict__ z,
                          const float* __restrict__ W1,
                          float* __restrict__ dinv, float* __restrict__ ys1){
  __shared__ float sW[D*D];
  for (int i = threadIdx.x; i < D*D; i += blockDim.x) sW[i] = W1[i];
  __syncthreads();
  int t = blockIdx.x*blockDim.x + threadIdx.x;
  int n = t >> 4, k = t & 15;
  if (n >= NN) return;
  int base = off_col[n], cnt = cnt_col[n];
  float s = 0.f;
  for (int i = k; i < cnt; i += 16) s += col_w[base+i];
  s = red16(s);
  float dv = 1.0f / sqrtf(1.0f + s);
  if (k == 0) dinv[n] = dv;
  float h = emb[z[n]*D + k];
  float acc = 0.f;
  #pragma unroll
  for (int j = 0; j < D; j++) acc += __shfl(h, j, 16)*sW[j*D+k];
  ys1[n*D+k] = dv*acc;
}

// conv1 gather (scaled) + MLP mid: ys2, masks
__global__ void k_conv1_mid(const int* __restrict__ col_src, const float* __restrict__ col_w,
                            const int* __restrict__ off_col, const int* __restrict__ cnt_col,
                            const float* __restrict__ dinv, const float* __restrict__ ys1,
                            const float* __restrict__ b1, const float* __restrict__ Wl1,
                            const float* __restrict__ bl1, const float* __restrict__ W2,
                            float* __restrict__ ys2, unsigned* __restrict__ masks){
  __shared__ float sWl1[D*D], sW2[D*D], sb1[D], sbl1[D];
  for (int i = threadIdx.x; i < D*D; i += blockDim.x){ sWl1[i] = Wl1[i]; sW2[i] = W2[i]; }
  if (threadIdx.x < D){ sb1[threadIdx.x] = b1[threadIdx.x]; sbl1[threadIdx.x] = bl1[threadIdx.x]; }
  __syncthreads();
  int t = blockIdx.x*blockDim.x + threadIdx.x;
  int n = t >> 4, k = t & 15;
  if (n >= NN) return;
  int base = off_col[n], cnt = cnt_col[n];
  float acc0 = 0.f, acc1 = 0.f;
  int i = 0;
  for (; i+1 < cnt; i += 2){
    int s0 = col_src[base+i],   s1 = col_src[base+i+1];
    float w0 = col_w[base+i],   w1 = col_w[base+i+1];
    acc0 += w0*ys1[s0*D+k];
    acc1 += w1*ys1[s1*D+k];
  }
  if (i < cnt) acc0 += col_w[base+i]*ys1[col_src[base+i]*D+k];
  float acc = acc0 + acc1;
  float dv = dinv[n];
  float u1 = dv*(acc + ys1[n*D+k]) + sb1[k];
  float h1 = leakyf(u1);
  float u2 = sbl1[k];
  #pragma unroll
  for (int j = 0; j < D; j++) u2 += __shfl(h1, j, 16)*sWl1[j*D+k];
  float h2 = leakyf(u2);
  float yo = 0.f;
  #pragma unroll
  for (int j = 0; j < D; j++) yo += __shfl(h2, j, 16)*sW2[j*D+k];
  ys2[n*D+k] = dv*yo;
  unsigned mm = ((u1 >= 0.f) ? (1u<<k) : 0u) | ((u2 >= 0.f) ? (1u<<(16+k)) : 0u);
  mm |= (unsigned)__shfl_xor((int)mm, 8, 16);
  mm |= (unsigned)__shfl_xor((int)mm, 4, 16);
  mm |= (unsigned)__shfl_xor((int)mm, 2, 16);
  mm |= (unsigned)__shfl_xor((int)mm, 1, 16);
  if (k == 0) masks[n] = mm;
}

// conv2 gather (scaled) + head + energy + head backward: ds3, gdiag_s
__global__ void k_conv2_out(const int* __restrict__ col_src, const float* __restrict__ col_w,
                            const int* __restrict__ off_col, const int* __restrict__ cnt_col,
                            const float* __restrict__ dinv, const float* __restrict__ ys2,
                            const int* __restrict__ batch,
                            const float* __restrict__ b2, const float* __restrict__ Wl2,
                            const float* __restrict__ bl2, const float* __restrict__ Wl3,
                            const float* __restrict__ bl3,
                            float* __restrict__ Eout, float* __restrict__ ds3,
                            float* __restrict__ gdiag){
  __shared__ float sWl2[D*4], sb2[D], sbl2[4], sWl3[4], sbl3s;
  if (threadIdx.x < D*4) sWl2[threadIdx.x] = Wl2[threadIdx.x];
  if (threadIdx.x < D) sb2[threadIdx.x] = b2[threadIdx.x];
  if (threadIdx.x < 4){ sbl2[threadIdx.x] = bl2[threadIdx.x]; sWl3[threadIdx.x] = Wl3[threadIdx.x]; }
  if (threadIdx.x == 0) sbl3s = bl3[0];
  __syncthreads();
  int t = blockIdx.x*blockDim.x + threadIdx.x;
  int n = t >> 4, k = t & 15;
  if (n >= NN) return;
  int base = off_col[n], cnt = cnt_col[n];
  float acc0 = 0.f, acc1 = 0.f;
  int i = 0;
  for (; i+1 < cnt; i += 2){
    int s0 = col_src[base+i],   s1 = col_src[base+i+1];
    float w0 = col_w[base+i],   w1 = col_w[base+i+1];
    acc0 += w0*ys2[s0*D+k];
    acc1 += w1*ys2[s1*D+k];
  }
  if (i < cnt) acc0 += col_w[base+i]*ys2[col_src[base+i]*D+k];
  float acc = acc0 + acc1;
  float dv = dinv[n];
  float ysk = ys2[n*D+k];
  float u3 = dv*(acc + ysk) + sb2[k];
  float h3 = leakyf(u3);
  float u40 = sbl2[0], u41 = sbl2[1], u42 = sbl2[2], u43 = sbl2[3];
  #pragma unroll
  for (int j = 0; j < D; j++){
    float hj = __shfl(h3, j, 16);
    u40 += hj*sWl2[j*4+0]; u41 += hj*sWl2[j*4+1];
    u42 += hj*sWl2[j*4+2]; u43 += hj*sWl2[j*4+3];
  }
  float h40 = leakyf(u40), h41 = leakyf(u41), h42 = leakyf(u42), h43 = leakyf(u43);
  float u5 = sbl3s + h40*sWl3[0] + h41*sWl3[1] + h42*sWl3[2] + h43*sWl3[3];
  float h5 = leakyf(u5);
  if (k == 0) atomicAdd(&Eout[batch[n]], h5);
  float du5 = dleakyf(u5);
  float d40 = du5*sWl3[0]*dleakyf(u40);
  float d41 = du5*sWl3[1]*dleakyf(u41);
  float d42 = du5*sWl3[2]*dleakyf(u42);
  float d43 = du5*sWl3[3]*dleakyf(u43);
  float g = d40*sWl2[k*4+0] + d41*sWl2[k*4+1] + d42*sWl2[k*4+2] + d43*sWl2[k*4+3];
  float d3 = g*dleakyf(u3);
  ds3[n*D+k] = dv*d3;
  float gd = red16(d3*ysk);          // gdiag_s = dv * (du3 . y2)
  if (k == 0) gdiag[n] = gd;
}

// ---- backward -----------------------------------------------------------
// FUSED: row pass 2 (gy2 accumulation + gn_row) + node mid chain -> ds1, gdiag
// gy2[n] is node-local to this lane group, so no intermediate buffer needed.
__global__ void k_bwd2mid(const int* __restrict__ row_dst, const float* __restrict__ row_w,
                          const int* __restrict__ off_row, const int* __restrict__ cnt_row,
                          const float* __restrict__ dinv, const float* __restrict__ ys1,
                          const float* __restrict__ ys2, const float* __restrict__ ds3,
                          const unsigned* __restrict__ masks,
                          const float* __restrict__ W2, const float* __restrict__ Wl1,
                          float* __restrict__ gn_row, float* __restrict__ ds1,
                          float* __restrict__ gdiag){
  __shared__ float sW2[D*D], sWl1[D*D];
  for (int i = threadIdx.x; i < D*D; i += blockDim.x){ sW2[i] = W2[i]; sWl1[i] = Wl1[i]; }
  __syncthreads();
  int t = blockIdx.x*blockDim.x + threadIdx.x;
  int n = t >> 4, k = t & 15;
  if (n >= NN) return;
  int base = off_row[n], cnt = cnt_row[n];
  float ysk = ys2[n*D+k];
  float gacc = 0.f;
  for (int i = 0; i < cnt; i++){
    int c = row_dst[base+i];
    float dval = ds3[c*D+k];
    gacc += row_w[base+i]*dval;
    float p = red16(dval*ysk);
    if (k == 0) gn_row[base+i] = p;
  }
  float dv = dinv[n];
  unsigned m = masks[n];
  float gy = dv*gacc + dv*ds3[n*D+k];      // gy2 + d2*du3
  float du2 = 0.f;
  #pragma unroll
  for (int j = 0; j < D; j++) du2 += __shfl(gy, j, 16)*sW2[k*D+j];
  du2 *= ((m>>(16+k))&1u) ? 1.0f : SLOPE;
  float du1 = 0.f;
  #pragma unroll
  for (int j = 0; j < D; j++) du1 += __shfl(du2, j, 16)*sWl1[k*D+j];
  du1 *= ((m>>k)&1u) ? 1.0f : SLOPE;
  float gd = red16(du1*ys1[n*D+k]);        // adds dv*(du1 . y1)
  if (k == 0) gdiag[n] += gd;
  ds1[n*D+k] = dv*du1;
}

// row pass 1: gn_row[slot] += ds1[c].ys1[n]; gdinv_row[n] = sum_out gns*w (raw)
__global__ void k_bwd1row(const int* __restrict__ row_dst, const float* __restrict__ row_w,
                          const int* __restrict__ off_row, const int* __restrict__ cnt_row,
                          const float* __restrict__ ys1, const float* __restrict__ ds1,
                          float* __restrict__ gn_row, float* __restrict__ gdinv_row){
  int t = blockIdx.x*blockDim.x + threadIdx.x;
  int n = t >> 4, k = t & 15;
  if (n >= NN) return;
  int base = off_row[n], cnt = cnt_row[n];
  float ysk = ys1[n*D+k];
  float gdr = 0.f;
  for (int i = 0; i < cnt; i++){
    int c = row_dst[base+i];
    float dval = ds1[c*D+k];
    float p = red16(dval*ysk);
    float g = gn_row[base+i] + p;        // broadcast read
    if (k == 0) gn_row[base+i] = g;
    gdr += g*row_w[base+i];
  }
  if (k == 0) gdinv_row[n] = gdr;
}

// col pass: gns_col copy (contiguous write), gdeg, packed node table (pos, gdeg)
__global__ void k_gdeg(const int* __restrict__ col_rp, const float* __restrict__ col_w,
                       const int* __restrict__ off_col, const int* __restrict__ cnt_col,
                       const float* __restrict__ gn_row, const float* __restrict__ gdinv_row,
                       const float* __restrict__ gdiag, const float* __restrict__ dinv,
                       const float* __restrict__ pos,
                       float* __restrict__ gns_col, float4* __restrict__ pn4){
  int t = blockIdx.x*blockDim.x + threadIdx.x;
  int n = t >> 4, k = t & 15;
  if (n >= NN) return;
  int base = off_col[n], cnt = cnt_col[n];
  float gc = 0.f;
  for (int i = k; i < cnt; i += 16){
    float g = gn_row[col_rp[base+i]];
    gc += g*col_w[base+i];
    gns_col[base+i] = g;
  }
  gc = red16(gc);
  if (k == 0){
    float dv = dinv[n];
    float arg = (gdinv_row[n] + gc)/dv + 2.0f*gdiag[n];  // gdiag holds dv*gdiag_true
    float gd = -0.5f*dv*dv*dv*arg;
    pn4[n] = make_float4(pos[3*n+0], pos[3*n+1], pos[3*n+2], gd);
  }
}

// force gather: coef = (gns + gdeg[col-node])/w, both directions
__global__ void k_force(const int* __restrict__ row_dst, const float* __restrict__ row_w,
                        const int* __restrict__ off_row, const int* __restrict__ cnt_row,
                        const int* __restrict__ col_src, const float* __restrict__ col_w,
                        const int* __restrict__ off_col, const int* __restrict__ cnt_col,
                        const float* __restrict__ gn_row, const float* __restrict__ gns_col,
                        const float4* __restrict__ pn4, float* __restrict__ F){
  int t = blockIdx.x*blockDim.x + threadIdx.x;
  int n = t >> 4, k = t & 15;
  if (n >= NN) return;
  float4 pn = pn4[n];
  float fx = 0.f, fy = 0.f, fz = 0.f;
  int base = off_row[n], cnt = cnt_row[n];
  for (int i = k; i < cnt; i += 16){
    int c = row_dst[base+i];
    float g = gn_row[base+i];
    float4 pc = pn4[c];
    float coef = (g + pc.w)/row_w[base+i];
    fx -= coef*(pn.x-pc.x); fy -= coef*(pn.y-pc.y); fz -= coef*(pn.z-pc.z);
  }
  base = off_col[n]; cnt = cnt_col[n];
  for (int i = k; i < cnt; i += 16){
    int r = col_src[base+i];
    float g = gns_col[base+i];
    float4 pr = pn4[r];
    float coef = (g + pn.w)/col_w[base+i];
    fx += coef*(pr.x-pn.x); fy += coef*(pr.y-pn.y); fz += coef*(pr.z-pn.z);
  }
  fx = red16(fx); fy = red16(fy); fz = red16(fz);
  if (k == 0){ F[3*n+0] = fx; F[3*n+1] = fy; F[3*n+2] = fz; }
}

extern "C" void kernel_launch(void* const* d_in, const int* in_sizes, int n_in,
                              void* d_out, int out_size, void* d_ws, size_t ws_size,
                              hipStream_t stream){
  const float* pos = (const float*)d_in[0];
  const float* emb = (const float*)d_in[1];
  const float* W1  = (const float*)d_in[2];
  const float* b1  = (const float*)d_in[3];
  const float* Wl1 = (const float*)d_in[4];
  const float* bl1 = (const float*)d_in[5];
  const float* W2  = (const float*)d_in[6];
  const float* b2  = (const float*)d_in[7];
  const float* Wl2 = (const float*)d_in[8];
  const float* bl2 = (const float*)d_in[9];
  const float* Wl3 = (const float*)d_in[10];
  const float* bl3 = (const float*)d_in[11];
  const int* z     = (const int*)d_in[12];
  const int* ei    = (const int*)d_in[13];
  const int* batch = (const int*)d_in[14];

  // workspace: ~74N + 6E words ~= 106.5 MB
  char* base = (char*)d_ws;
  size_t o = 0;
  auto alloc = [&](size_t words){ o = (o + 3) & ~(size_t)3; void* p = base + o*4; o += words; return p; };
  int*   cnt_row   = (int*)alloc(NN);
  int*   cnt_col   = (int*)alloc(NN);
  int*   off_row   = (int*)alloc(NN);
  int*   off_col   = (int*)alloc(NN);
  int*   cur_row   = (int*)alloc(NN);
  int*   cur_col   = (int*)alloc(NN);
  int*   bsum      = (int*)alloc(1024);
  float* dinv      = (float*)alloc(NN);
  float* gdiag     = (float*)alloc(NN);
  float* gdinv_row = (float*)alloc(NN);
  unsigned* masks  = (unsigned*)alloc(NN);
  float* ys1       = (float*)alloc(16*NN);
  float* ys2       = (float*)alloc(16*NN);
  float* ds3       = (float*)alloc(16*NN);
  float* ds1       = (float*)alloc(16*NN);
  int*   row_dst   = (int*)alloc(NE);
  float* row_w     = (float*)alloc(NE);
  int*   col_src   = (int*)alloc(NE);
  int*   col_rp    = (int*)alloc(NE);
  float* col_w     = (float*)alloc(NE);
  float* gn_row    = (float*)alloc(NE);
  // aliases (lifetimes disjoint): gns_col over ys1+ys2 (E == 32N, both dead
  // after k_bwd1row); pn4 over ds3 (dead after k_bwd2mid)
  float*  gns_col = ys1;
  float4* pn4     = (float4*)ds3;

  float* Eout = (float*)d_out;
  float* F = Eout + NG;

  int nbN   = (NN + BT - 1)/BT;        // 391
  int nbE   = (NE + BT - 1)/BT;
  int nbN16 = (NN*16 + BT - 1)/BT;     // 6250

  k_fill<<<(2*NN + BT - 1)/BT, BT, 0, stream>>>((float*)cnt_row, 2*NN, 0.0f);
  k_fill<<<(NG + BT - 1)/BT, BT, 0, stream>>>(Eout, NG, 0.0f);

  // CSR build
  k_count<<<nbE, BT, 0, stream>>>(ei, cnt_row, cnt_col);
  k_blocksum<<<dim3(nbN,2), BT, 0, stream>>>(cnt_row, cnt_col, bsum);
  k_scan_bsum<<<dim3(1,2), 512, 0, stream>>>(bsum, nbN);
  k_offsets<<<dim3(nbN,2), BT, 0, stream>>>(cnt_row, cnt_col, bsum,
                                            off_row, off_col, cur_row, cur_col);
  k_place<<<nbE, BT, 0, stream>>>(ei, pos, cur_row, cur_col,
                                  row_dst, row_w, col_src, col_rp, col_w);

  // forward
  k_dinv_y1<<<nbN16, BT, 0, stream>>>(col_w, off_col, cnt_col, emb, z, W1, dinv, ys1);
  k_conv1_mid<<<nbN16, BT, 0, stream>>>(col_src, col_w, off_col, cnt_col, dinv, ys1,
                                        b1, Wl1, bl1, W2, ys2, masks);
  k_conv2_out<<<nbN16, BT, 0, stream>>>(col_src, col_w, off_col, cnt_col, dinv, ys2,
                                        batch, b2, Wl2, bl2, Wl3, bl3, Eout, ds3, gdiag);

  // backward
  k_bwd2mid<<<nbN16, BT, 0, stream>>>(row_dst, row_w, off_row, cnt_row, dinv, ys1, ys2,
                                      ds3, masks, W2, Wl1, gn_row, ds1, gdiag);
  k_bwd1row<<<nbN16, BT, 0, stream>>>(row_dst, row_w, off_row, cnt_row, ys1, ds1,
                                      gn_row, gdinv_row);
  k_gdeg<<<nbN16, BT, 0, stream>>>(col_rp, col_w, off_col, cnt_col, gn_row, gdinv_row,
                                   gdiag, dinv, pos, gns_col, pn4);
  k_force<<<nbN16, BT, 0, stream>>>(row_dst, row_w, off_row, cnt_row,
                                    col_src, col_w, off_col, cnt_col,
                                    gn_row, gns_col, pn4, F);
}

// Round 5
// 1274.923 us; speedup vs baseline: 1.8946x; 1.0484x over previous
//
#include <hip/hip_runtime.h>
#include <math.h>

#define NN 100000
#define NE 3200000
#define NG 512
#define D 16
#define SLOPE 0.01f
#define BT 256

__device__ __forceinline__ float leakyf(float x){ return x >= 0.0f ? x : SLOPE*x; }
__device__ __forceinline__ float dleakyf(float x){ return x >= 0.0f ? 1.0f : SLOPE; }

__device__ __forceinline__ float red16(float v){
  v += __shfl_xor(v, 8, 16);
  v += __shfl_xor(v, 4, 16);
  v += __shfl_xor(v, 2, 16);
  v += __shfl_xor(v, 1, 16);
  return v;
}

// pos (N,3) -> pos4 (N,4) aligned 16B rows
__global__ void k_pos4(const float* __restrict__ pos, float4* __restrict__ pos4){
  int n = blockIdx.x*blockDim.x + threadIdx.x;
  if (n >= NN) return;
  pos4[n] = make_float4(pos[3*n+0], pos[3*n+1], pos[3*n+2], 0.0f);
}

// ---- CSR build ----------------------------------------------------------
// 4 edges/thread, int4 loads
__global__ void k_count(const int* __restrict__ ei, int* __restrict__ cnt_row,
                        int* __restrict__ cnt_col){
  int t = blockIdx.x*blockDim.x + threadIdx.x;
  if (t >= NE/4) return;
  int4 r4 = ((const int4*)ei)[t];
  int4 c4 = ((const int4*)(ei + NE))[t];
  atomicAdd(&cnt_row[r4.x], 1); atomicAdd(&cnt_row[r4.y], 1);
  atomicAdd(&cnt_row[r4.z], 1); atomicAdd(&cnt_row[r4.w], 1);
  atomicAdd(&cnt_col[c4.x], 1); atomicAdd(&cnt_col[c4.y], 1);
  atomicAdd(&cnt_col[c4.z], 1); atomicAdd(&cnt_col[c4.w], 1);
}

__global__ void k_blocksum(const int* __restrict__ cnt_row, const int* __restrict__ cnt_col,
                           int* __restrict__ bsum){
  const int* src = blockIdx.y ? cnt_col : cnt_row;
  __shared__ int s[BT];
  int i = blockIdx.x*BT + threadIdx.x;
  s[threadIdx.x] = (i < NN) ? src[i] : 0;
  __syncthreads();
  for (int off = BT/2; off > 0; off >>= 1){
    if (threadIdx.x < off) s[threadIdx.x] += s[threadIdx.x+off];
    __syncthreads();
  }
  if (threadIdx.x == 0) bsum[blockIdx.y*512 + blockIdx.x] = s[0];
}

__global__ void k_scan_bsum(int* __restrict__ bsum, int nb){
  int* b = bsum + blockIdx.y*512;
  __shared__ int s0[512], s1[512];
  int tid = threadIdx.x;
  int v = (tid < nb) ? b[tid] : 0;
  s0[tid] = v; __syncthreads();
  int rd = 0;
  for (int off = 1; off < 512; off <<= 1){
    int x = rd ? s1[tid] : s0[tid];
    if (tid >= off) x += rd ? s1[tid-off] : s0[tid-off];
    if (rd) s0[tid] = x; else s1[tid] = x;
    __syncthreads();
    rd ^= 1;
  }
  int incl = rd ? s1[tid] : s0[tid];
  if (tid < nb) b[tid] = incl - v;
}

__global__ void k_offsets(const int* __restrict__ cnt_row, const int* __restrict__ cnt_col,
                          const int* __restrict__ bsum,
                          int* __restrict__ off_row, int* __restrict__ off_col,
                          int* __restrict__ cur_row, int* __restrict__ cur_col){
  const int* src  = blockIdx.y ? cnt_col : cnt_row;
  int* offd = blockIdx.y ? off_col : off_row;
  int* curd = blockIdx.y ? cur_col : cur_row;
  __shared__ int s0[BT], s1[BT];
  int tid = threadIdx.x;
  int i = blockIdx.x*BT + tid;
  int v = (i < NN) ? src[i] : 0;
  s0[tid] = v; __syncthreads();
  int rd = 0;
  for (int off = 1; off < BT; off <<= 1){
    int x = rd ? s1[tid] : s0[tid];
    if (tid >= off) x += rd ? s1[tid-off] : s0[tid-off];
    if (rd) s0[tid] = x; else s1[tid] = x;
    __syncthreads();
    rd ^= 1;
  }
  int incl = rd ? s1[tid] : s0[tid];
  if (i < NN){
    int o = bsum[blockIdx.y*512 + blockIdx.x] + incl - v;
    offd[i] = o; curd[i] = o;
  }
}

// SoA scattered 4B stores (measured fastest layout, r2 vs r3); aligned pos4 gathers
__global__ void k_place(const int* __restrict__ ei, const float4* __restrict__ pos4,
                        int* __restrict__ cur_row, int* __restrict__ cur_col,
                        int* __restrict__ row_dst, float* __restrict__ row_w,
                        int* __restrict__ col_src, int* __restrict__ col_rp,
                        float* __restrict__ col_w){
  int e = blockIdx.x*blockDim.x + threadIdx.x;
  if (e >= NE) return;
  int r = ei[e], c = ei[NE+e];
  float4 pr = pos4[r], pc = pos4[c];
  float dx = pr.x-pc.x, dy = pr.y-pc.y, dz = pr.z-pc.z;
  float w = sqrtf(dx*dx+dy*dy+dz*dz);
  int p = atomicAdd(&cur_row[r], 1);
  int q = atomicAdd(&cur_col[c], 1);
  row_dst[p] = c; row_w[p] = w;
  col_src[q] = r; col_rp[q] = p; col_w[q] = w;
}

// ---- forward ------------------------------------------------------------
__global__ void k_dinv_y1(const float* __restrict__ col_w, const int* __restrict__ off_col,
                          const int* __restrict__ cnt_col,
                          const float* __restrict__ emb, const int* __restrict__ z,
                          const float* __restrict__ W1,
                          float* __restrict__ dinv, float* __restrict__ ys1){
  __shared__ float sW[D*D];
  for (int i = threadIdx.x; i < D*D; i += blockDim.x) sW[i] = W1[i];
  __syncthreads();
  int t = blockIdx.x*blockDim.x + threadIdx.x;
  int n = t >> 4, k = t & 15;
  if (n >= NN) return;
  int base = off_col[n], cnt = cnt_col[n];
  float s = 0.f;
  for (int i = k; i < cnt; i += 16) s += col_w[base+i];
  s = red16(s);
  float dv = 1.0f / sqrtf(1.0f + s);
  if (k == 0) dinv[n] = dv;
  float h = emb[z[n]*D + k];
  float acc = 0.f;
  #pragma unroll
  for (int j = 0; j < D; j++) acc += __shfl(h, j, 16)*sW[j*D+k];
  ys1[n*D+k] = dv*acc;
}

// conv1 gather (scaled) + MLP mid: ys2, masks
__global__ void k_conv1_mid(const int* __restrict__ col_src, const float* __restrict__ col_w,
                            const int* __restrict__ off_col, const int* __restrict__ cnt_col,
                            const float* __restrict__ dinv, const float* __restrict__ ys1,
                            const float* __restrict__ b1, const float* __restrict__ Wl1,
                            const float* __restrict__ bl1, const float* __restrict__ W2,
                            float* __restrict__ ys2, unsigned* __restrict__ masks){
  __shared__ float sWl1[D*D], sW2[D*D], sb1[D], sbl1[D];
  for (int i = threadIdx.x; i < D*D; i += blockDim.x){ sWl1[i] = Wl1[i]; sW2[i] = W2[i]; }
  if (threadIdx.x < D){ sb1[threadIdx.x] = b1[threadIdx.x]; sbl1[threadIdx.x] = bl1[threadIdx.x]; }
  __syncthreads();
  int t = blockIdx.x*blockDim.x + threadIdx.x;
  int n = t >> 4, k = t & 15;
  if (n >= NN) return;
  int base = off_col[n], cnt = cnt_col[n];
  float acc0 = 0.f, acc1 = 0.f;
  int i = 0;
  for (; i+1 < cnt; i += 2){
    int s0 = col_src[base+i],   s1 = col_src[base+i+1];
    float w0 = col_w[base+i],   w1 = col_w[base+i+1];
    acc0 += w0*ys1[s0*D+k];
    acc1 += w1*ys1[s1*D+k];
  }
  if (i < cnt) acc0 += col_w[base+i]*ys1[col_src[base+i]*D+k];
  float acc = acc0 + acc1;
  float dv = dinv[n];
  float u1 = dv*(acc + ys1[n*D+k]) + sb1[k];
  float h1 = leakyf(u1);
  float u2 = sbl1[k];
  #pragma unroll
  for (int j = 0; j < D; j++) u2 += __shfl(h1, j, 16)*sWl1[j*D+k];
  float h2 = leakyf(u2);
  float yo = 0.f;
  #pragma unroll
  for (int j = 0; j < D; j++) yo += __shfl(h2, j, 16)*sW2[j*D+k];
  ys2[n*D+k] = dv*yo;
  unsigned mm = ((u1 >= 0.f) ? (1u<<k) : 0u) | ((u2 >= 0.f) ? (1u<<(16+k)) : 0u);
  mm |= (unsigned)__shfl_xor((int)mm, 8, 16);
  mm |= (unsigned)__shfl_xor((int)mm, 4, 16);
  mm |= (unsigned)__shfl_xor((int)mm, 2, 16);
  mm |= (unsigned)__shfl_xor((int)mm, 1, 16);
  if (k == 0) masks[n] = mm;
}

// conv2 gather (scaled) + head + energy + head backward: ds3, gdiag_s
__global__ void k_conv2_out(const int* __restrict__ col_src, const float* __restrict__ col_w,
                            const int* __restrict__ off_col, const int* __restrict__ cnt_col,
                            const float* __restrict__ dinv, const float* __restrict__ ys2,
                            const int* __restrict__ batch,
                            const float* __restrict__ b2, const float* __restrict__ Wl2,
                            const float* __restrict__ bl2, const float* __restrict__ Wl3,
                            const float* __restrict__ bl3,
                            float* __restrict__ Eout, float* __restrict__ ds3,
                            float* __restrict__ gdiag){
  __shared__ float sWl2[D*4], sb2[D], sbl2[4], sWl3[4], sbl3s;
  if (threadIdx.x < D*4) sWl2[threadIdx.x] = Wl2[threadIdx.x];
  if (threadIdx.x < D) sb2[threadIdx.x] = b2[threadIdx.x];
  if (threadIdx.x < 4){ sbl2[threadIdx.x] = bl2[threadIdx.x]; sWl3[threadIdx.x] = Wl3[threadIdx.x]; }
  if (threadIdx.x == 0) sbl3s = bl3[0];
  __syncthreads();
  int t = blockIdx.x*blockDim.x + threadIdx.x;
  int n = t >> 4, k = t & 15;
  if (n >= NN) return;
  int base = off_col[n], cnt = cnt_col[n];
  float acc0 = 0.f, acc1 = 0.f;
  int i = 0;
  for (; i+1 < cnt; i += 2){
    int s0 = col_src[base+i],   s1 = col_src[base+i+1];
    float w0 = col_w[base+i],   w1 = col_w[base+i+1];
    acc0 += w0*ys2[s0*D+k];
    acc1 += w1*ys2[s1*D+k];
  }
  if (i < cnt) acc0 += col_w[base+i]*ys2[col_src[base+i]*D+k];
  float acc = acc0 + acc1;
  float dv = dinv[n];
  float ysk = ys2[n*D+k];
  float u3 = dv*(acc + ysk) + sb2[k];
  float h3 = leakyf(u3);
  float u40 = sbl2[0], u41 = sbl2[1], u42 = sbl2[2], u43 = sbl2[3];
  #pragma unroll
  for (int j = 0; j < D; j++){
    float hj = __shfl(h3, j, 16);
    u40 += hj*sWl2[j*4+0]; u41 += hj*sWl2[j*4+1];
    u42 += hj*sWl2[j*4+2]; u43 += hj*sWl2[j*4+3];
  }
  float h40 = leakyf(u40), h41 = leakyf(u41), h42 = leakyf(u42), h43 = leakyf(u43);
  float u5 = sbl3s + h40*sWl3[0] + h41*sWl3[1] + h42*sWl3[2] + h43*sWl3[3];
  float h5 = leakyf(u5);
  if (k == 0) atomicAdd(&Eout[batch[n]], h5);
  float du5 = dleakyf(u5);
  float d40 = du5*sWl3[0]*dleakyf(u40);
  float d41 = du5*sWl3[1]*dleakyf(u41);
  float d42 = du5*sWl3[2]*dleakyf(u42);
  float d43 = du5*sWl3[3]*dleakyf(u43);
  float g = d40*sWl2[k*4+0] + d41*sWl2[k*4+1] + d42*sWl2[k*4+2] + d43*sWl2[k*4+3];
  float d3 = g*dleakyf(u3);
  ds3[n*D+k] = dv*d3;
  float gd = red16(d3*ysk);          // gdiag_s = dv * (du3 . y2)
  if (k == 0) gdiag[n] = gd;
}

// ---- backward -----------------------------------------------------------
// FUSED: row pass 2 (gy2 accumulation + gn_row) + node mid chain -> ds1, gdiag
__global__ void k_bwd2mid(const int* __restrict__ row_dst, const float* __restrict__ row_w,
                          const int* __restrict__ off_row, const int* __restrict__ cnt_row,
                          const float* __restrict__ dinv, const float* __restrict__ ys1,
                          const float* __restrict__ ys2, const float* __restrict__ ds3,
                          const unsigned* __restrict__ masks,
                          const float* __restrict__ W2, const float* __restrict__ Wl1,
                          float* __restrict__ gn_row, float* __restrict__ ds1,
                          float* __restrict__ gdiag){
  __shared__ float sW2[D*D], sWl1[D*D];
  for (int i = threadIdx.x; i < D*D; i += blockDim.x){ sW2[i] = W2[i]; sWl1[i] = Wl1[i]; }
  __syncthreads();
  int t = blockIdx.x*blockDim.x + threadIdx.x;
  int n = t >> 4, k = t & 15;
  if (n >= NN) return;
  int base = off_row[n], cnt = cnt_row[n];
  float ysk = ys2[n*D+k];
  float gacc = 0.f;
  for (int i = 0; i < cnt; i++){
    int c = row_dst[base+i];
    float dval = ds3[c*D+k];
    gacc += row_w[base+i]*dval;
    float p = red16(dval*ysk);
    if (k == 0) gn_row[base+i] = p;
  }
  float dv = dinv[n];
  unsigned m = masks[n];
  float gy = dv*gacc + dv*ds3[n*D+k];      // gy2 + d2*du3
  float du2 = 0.f;
  #pragma unroll
  for (int j = 0; j < D; j++) du2 += __shfl(gy, j, 16)*sW2[k*D+j];
  du2 *= ((m>>(16+k))&1u) ? 1.0f : SLOPE;
  float du1 = 0.f;
  #pragma unroll
  for (int j = 0; j < D; j++) du1 += __shfl(du2, j, 16)*sWl1[k*D+j];
  du1 *= ((m>>k)&1u) ? 1.0f : SLOPE;
  float gd = red16(du1*ys1[n*D+k]);        // adds dv*(du1 . y1)
  if (k == 0) gdiag[n] += gd;
  ds1[n*D+k] = dv*du1;
}

// row pass 1: gn_row[slot] += ds1[c].ys1[n]; gdinv_row[n] = sum_out gns*w (raw)
__global__ void k_bwd1row(const int* __restrict__ row_dst, const float* __restrict__ row_w,
                          const int* __restrict__ off_row, const int* __restrict__ cnt_row,
                          const float* __restrict__ ys1, const float* __restrict__ ds1,
                          float* __restrict__ gn_row, float* __restrict__ gdinv_row){
  int t = blockIdx.x*blockDim.x + threadIdx.x;
  int n = t >> 4, k = t & 15;
  if (n >= NN) return;
  int base = off_row[n], cnt = cnt_row[n];
  float ysk = ys1[n*D+k];
  float gdr = 0.f;
  for (int i = 0; i < cnt; i++){
    int c = row_dst[base+i];
    float dval = ds1[c*D+k];
    float p = red16(dval*ysk);
    float g = gn_row[base+i] + p;        // broadcast read
    if (k == 0) gn_row[base+i] = g;
    gdr += g*row_w[base+i];
  }
  if (k == 0) gdinv_row[n] = gdr;
}

// col pass: gns_col copy (contiguous write), gdeg, packed node table (pos, gdeg)
__global__ void k_gdeg(const int* __restrict__ col_rp, const float* __restrict__ col_w,
                       const int* __restrict__ off_col, const int* __restrict__ cnt_col,
                       const float* __restrict__ gn_row, const float* __restrict__ gdinv_row,
                       const float* __restrict__ gdiag, const float* __restrict__ dinv,
                       const float4* __restrict__ pos4,
                       float* __restrict__ gns_col, float4* __restrict__ pn4){
  int t = blockIdx.x*blockDim.x + threadIdx.x;
  int n = t >> 4, k = t & 15;
  if (n >= NN) return;
  int base = off_col[n], cnt = cnt_col[n];
  float gc = 0.f;
  for (int i = k; i < cnt; i += 16){
    float g = gn_row[col_rp[base+i]];
    gc += g*col_w[base+i];
    gns_col[base+i] = g;
  }
  gc = red16(gc);
  if (k == 0){
    float dv = dinv[n];
    float arg = (gdinv_row[n] + gc)/dv + 2.0f*gdiag[n];  // gdiag holds dv*gdiag_true
    float gd = -0.5f*dv*dv*dv*arg;
    float4 p = pos4[n];
    pn4[n] = make_float4(p.x, p.y, p.z, gd);
  }
}

// force gather: coef = (gns + gdeg[col-node])/w, both directions
__global__ void k_force(const int* __restrict__ row_dst, const float* __restrict__ row_w,
                        const int* __restrict__ off_row, const int* __restrict__ cnt_row,
                        const int* __restrict__ col_src, const float* __restrict__ col_w,
                        const int* __restrict__ off_col, const int* __restrict__ cnt_col,
                        const float* __restrict__ gn_row, const float* __restrict__ gns_col,
                        const float4* __restrict__ pn4, float* __restrict__ F){
  int t = blockIdx.x*blockDim.x + threadIdx.x;
  int n = t >> 4, k = t & 15;
  if (n >= NN) return;
  float4 pn = pn4[n];
  float fx = 0.f, fy = 0.f, fz = 0.f;
  int base = off_row[n], cnt = cnt_row[n];
  for (int i = k; i < cnt; i += 16){
    int c = row_dst[base+i];
    float g = gn_row[base+i];
    float4 pc = pn4[c];
    float coef = (g + pc.w)/row_w[base+i];
    fx -= coef*(pn.x-pc.x); fy -= coef*(pn.y-pc.y); fz -= coef*(pn.z-pc.z);
  }
  base = off_col[n]; cnt = cnt_col[n];
  for (int i = k; i < cnt; i += 16){
    int r = col_src[base+i];
    float g = gns_col[base+i];
    float4 pr = pn4[r];
    float coef = (g + pn.w)/col_w[base+i];
    fx += coef*(pr.x-pn.x); fy += coef*(pr.y-pn.y); fz += coef*(pr.z-pn.z);
  }
  fx = red16(fx); fy = red16(fy); fz = red16(fz);
  if (k == 0){ F[3*n+0] = fx; F[3*n+1] = fy; F[3*n+2] = fz; }
}

extern "C" void kernel_launch(void* const* d_in, const int* in_sizes, int n_in,
                              void* d_out, int out_size, void* d_ws, size_t ws_size,
                              hipStream_t stream){
  const float* pos = (const float*)d_in[0];
  const float* emb = (const float*)d_in[1];
  const float* W1  = (const float*)d_in[2];
  const float* b1  = (const float*)d_in[3];
  const float* Wl1 = (const float*)d_in[4];
  const float* bl1 = (const float*)d_in[5];
  const float* W2  = (const float*)d_in[6];
  const float* b2  = (const float*)d_in[7];
  const float* Wl2 = (const float*)d_in[8];
  const float* bl2 = (const float*)d_in[9];
  const float* Wl3 = (const float*)d_in[10];
  const float* bl3 = (const float*)d_in[11];
  const int* z     = (const int*)d_in[12];
  const int* ei    = (const int*)d_in[13];
  const int* batch = (const int*)d_in[14];

  // workspace: ~78N + 6E words ~= 108 MB
  char* base = (char*)d_ws;
  size_t o = 0;
  auto alloc = [&](size_t words){ o = (o + 3) & ~(size_t)3; void* p = base + o*4; o += words; return p; };
  int*   cnt_row   = (int*)alloc(NN);
  int*   cnt_col   = (int*)alloc(NN);
  int*   off_row   = (int*)alloc(NN);
  int*   off_col   = (int*)alloc(NN);
  int*   cur_row   = (int*)alloc(NN);
  int*   cur_col   = (int*)alloc(NN);
  int*   bsum      = (int*)alloc(1024);
  float* dinv      = (float*)alloc(NN);
  float* gdiag     = (float*)alloc(NN);
  float* gdinv_row = (float*)alloc(NN);
  unsigned* masks  = (unsigned*)alloc(NN);
  float4* pos4     = (float4*)alloc(4*NN);
  float* ys1       = (float*)alloc(16*NN);
  float* ys2       = (float*)alloc(16*NN);
  float* ds3       = (float*)alloc(16*NN);
  float* ds1       = (float*)alloc(16*NN);
  int*   row_dst   = (int*)alloc(NE);
  float* row_w     = (float*)alloc(NE);
  int*   col_src   = (int*)alloc(NE);
  int*   col_rp    = (int*)alloc(NE);
  float* col_w     = (float*)alloc(NE);
  float* gn_row    = (float*)alloc(NE);
  // aliases (lifetimes disjoint): gns_col over ys1+ys2 (E == 32N, both dead
  // after k_bwd1row); pn4 over ds3 (dead after k_bwd2mid)
  float*  gns_col = ys1;
  float4* pn4     = (float4*)ds3;

  float* Eout = (float*)d_out;
  float* F = Eout + NG;

  int nbN   = (NN + BT - 1)/BT;        // 391
  int nbE   = (NE + BT - 1)/BT;
  int nbE4  = (NE/4 + BT - 1)/BT;
  int nbN16 = (NN*16 + BT - 1)/BT;     // 6250

  // zero counters + energy output (memset nodes are graph-capturable)
  hipMemsetAsync(cnt_row, 0, 2*(size_t)NN*4, stream);
  hipMemsetAsync(Eout, 0, (size_t)NG*4, stream);

  k_pos4<<<nbN, BT, 0, stream>>>(pos, pos4);

  // CSR build
  k_count<<<nbE4, BT, 0, stream>>>(ei, cnt_row, cnt_col);
  k_blocksum<<<dim3(nbN,2), BT, 0, stream>>>(cnt_row, cnt_col, bsum);
  k_scan_bsum<<<dim3(1,2), 512, 0, stream>>>(bsum, nbN);
  k_offsets<<<dim3(nbN,2), BT, 0, stream>>>(cnt_row, cnt_col, bsum,
                                            off_row, off_col, cur_row, cur_col);
  k_place<<<nbE, BT, 0, stream>>>(ei, pos4, cur_row, cur_col,
                                  row_dst, row_w, col_src, col_rp, col_w);

  // forward
  k_dinv_y1<<<nbN16, BT, 0, stream>>>(col_w, off_col, cnt_col, emb, z, W1, dinv, ys1);
  k_conv1_mid<<<nbN16, BT, 0, stream>>>(col_src, col_w, off_col, cnt_col, dinv, ys1,
                                        b1, Wl1, bl1, W2, ys2, masks);
  k_conv2_out<<<nbN16, BT, 0, stream>>>(col_src, col_w, off_col, cnt_col, dinv, ys2,
                                        batch, b2, Wl2, bl2, Wl3, bl3, Eout, ds3, gdiag);

  // backward
  k_bwd2mid<<<nbN16, BT, 0, stream>>>(row_dst, row_w, off_row, cnt_row, dinv, ys1, ys2,
                                      ds3, masks, W2, Wl1, gn_row, ds1, gdiag);
  k_bwd1row<<<nbN16, BT, 0, stream>>>(row_dst, row_w, off_row, cnt_row, ys1, ds1,
                                      gn_row, gdinv_row);
  k_gdeg<<<nbN16, BT, 0, stream>>>(col_rp, col_w, off_col, cnt_col, gn_row, gdinv_row,
                                   gdiag, dinv, pos4, gns_col, pn4);
  k_force<<<nbN16, BT, 0, stream>>>(row_dst, row_w, off_row, cnt_row,
                                    col_src, col_w, off_col, cnt_col,
                                    gn_row, gns_col, pn4, F);
}

// Round 6
// 1157.826 us; speedup vs baseline: 2.0862x; 1.1011x over previous
//
#include <hip/hip_runtime.h>
#include <math.h>

#define NN 100000
#define NE 3200000
#define NG 512
#define D 16
#define SLOPE 0.01f
#define BT 256

__device__ __forceinline__ float leakyf(float x){ return x >= 0.0f ? x : SLOPE*x; }
__device__ __forceinline__ float dleakyf(float x){ return x >= 0.0f ? 1.0f : SLOPE; }

__device__ __forceinline__ float red16(float v){
  v += __shfl_xor(v, 8, 16);
  v += __shfl_xor(v, 4, 16);
  v += __shfl_xor(v, 2, 16);
  v += __shfl_xor(v, 1, 16);
  return v;
}

// pos (N,3) -> pos4 (N,4) aligned 16B rows
__global__ void k_pos4(const float* __restrict__ pos, float4* __restrict__ pos4){
  int n = blockIdx.x*blockDim.x + threadIdx.x;
  if (n >= NN) return;
  pos4[n] = make_float4(pos[3*n+0], pos[3*n+1], pos[3*n+2], 0.0f);
}

// ---- CSR build ----------------------------------------------------------
__global__ void k_count(const int* __restrict__ ei, int* __restrict__ cnt_row,
                        int* __restrict__ cnt_col){
  int t = blockIdx.x*blockDim.x + threadIdx.x;
  if (t >= NE/4) return;
  int4 r4 = ((const int4*)ei)[t];
  int4 c4 = ((const int4*)(ei + NE))[t];
  atomicAdd(&cnt_row[r4.x], 1); atomicAdd(&cnt_row[r4.y], 1);
  atomicAdd(&cnt_row[r4.z], 1); atomicAdd(&cnt_row[r4.w], 1);
  atomicAdd(&cnt_col[c4.x], 1); atomicAdd(&cnt_col[c4.y], 1);
  atomicAdd(&cnt_col[c4.z], 1); atomicAdd(&cnt_col[c4.w], 1);
}

__global__ void k_blocksum(const int* __restrict__ cnt_row, const int* __restrict__ cnt_col,
                           int* __restrict__ bsum){
  const int* src = blockIdx.y ? cnt_col : cnt_row;
  __shared__ int s[BT];
  int i = blockIdx.x*BT + threadIdx.x;
  s[threadIdx.x] = (i < NN) ? src[i] : 0;
  __syncthreads();
  for (int off = BT/2; off > 0; off >>= 1){
    if (threadIdx.x < off) s[threadIdx.x] += s[threadIdx.x+off];
    __syncthreads();
  }
  if (threadIdx.x == 0) bsum[blockIdx.y*512 + blockIdx.x] = s[0];
}

__global__ void k_scan_bsum(int* __restrict__ bsum, int nb){
  int* b = bsum + blockIdx.y*512;
  __shared__ int s0[512], s1[512];
  int tid = threadIdx.x;
  int v = (tid < nb) ? b[tid] : 0;
  s0[tid] = v; __syncthreads();
  int rd = 0;
  for (int off = 1; off < 512; off <<= 1){
    int x = rd ? s1[tid] : s0[tid];
    if (tid >= off) x += rd ? s1[tid-off] : s0[tid-off];
    if (rd) s0[tid] = x; else s1[tid] = x;
    __syncthreads();
    rd ^= 1;
  }
  int incl = rd ? s1[tid] : s0[tid];
  if (tid < nb) b[tid] = incl - v;
}

__global__ void k_offsets(const int* __restrict__ cnt_row, const int* __restrict__ cnt_col,
                          const int* __restrict__ bsum,
                          int* __restrict__ off_row, int* __restrict__ off_col,
                          int* __restrict__ cur_row, int* __restrict__ cur_col){
  const int* src  = blockIdx.y ? cnt_col : cnt_row;
  int* offd = blockIdx.y ? off_col : off_row;
  int* curd = blockIdx.y ? cur_col : cur_row;
  __shared__ int s0[BT], s1[BT];
  int tid = threadIdx.x;
  int i = blockIdx.x*BT + tid;
  int v = (i < NN) ? src[i] : 0;
  s0[tid] = v; __syncthreads();
  int rd = 0;
  for (int off = 1; off < BT; off <<= 1){
    int x = rd ? s1[tid] : s0[tid];
    if (tid >= off) x += rd ? s1[tid-off] : s0[tid-off];
    if (rd) s0[tid] = x; else s1[tid] = x;
    __syncthreads();
    rd ^= 1;
  }
  int incl = rd ? s1[tid] : s0[tid];
  if (i < NN){
    int o = bsum[blockIdx.y*512 + blockIdx.x] + incl - v;
    offd[i] = o; curd[i] = o;
  }
}

// SoA scattered 4B stores (measured fastest layout, r2 vs r3); aligned pos4 gathers
__global__ void k_place(const int* __restrict__ ei, const float4* __restrict__ pos4,
                        int* __restrict__ cur_row, int* __restrict__ cur_col,
                        int* __restrict__ row_dst, float* __restrict__ row_w,
                        int* __restrict__ col_src, int* __restrict__ col_rp,
                        float* __restrict__ col_w){
  int e = blockIdx.x*blockDim.x + threadIdx.x;
  if (e >= NE) return;
  int r = ei[e], c = ei[NE+e];
  float4 pr = pos4[r], pc = pos4[c];
  float dx = pr.x-pc.x, dy = pr.y-pc.y, dz = pr.z-pc.z;
  float w = sqrtf(dx*dx+dy*dy+dz*dz);
  int p = atomicAdd(&cur_row[r], 1);
  int q = atomicAdd(&cur_col[c], 1);
  row_dst[p] = c; row_w[p] = w;
  col_src[q] = r; col_rp[q] = p; col_w[q] = w;
}

// ---- forward ------------------------------------------------------------
__global__ void k_dinv_y1(const float* __restrict__ col_w, const int* __restrict__ off_col,
                          const int* __restrict__ cnt_col,
                          const float* __restrict__ emb, const int* __restrict__ z,
                          const float* __restrict__ W1,
                          float* __restrict__ dinv, float* __restrict__ ys1){
  __shared__ float sW[D*D];
  for (int i = threadIdx.x; i < D*D; i += blockDim.x) sW[i] = W1[i];
  __syncthreads();
  int t = blockIdx.x*blockDim.x + threadIdx.x;
  int n = t >> 4, k = t & 15;
  if (n >= NN) return;
  int base = off_col[n], cnt = cnt_col[n];
  float s = 0.f;
  for (int i = k; i < cnt; i += 16) s += col_w[base+i];
  s = red16(s);
  float dv = 1.0f / sqrtf(1.0f + s);
  if (k == 0) dinv[n] = dv;
  float h = emb[z[n]*D + k];
  float acc = 0.f;
  #pragma unroll
  for (int j = 0; j < D; j++) acc += __shfl(h, j, 16)*sW[j*D+k];
  ys1[n*D+k] = dv*acc;
}

// conv1 gather (16-edge blocks: coalesced src/w loads + shfl broadcast) + MLP mid
__global__ void k_conv1_mid(const int* __restrict__ col_src, const float* __restrict__ col_w,
                            const int* __restrict__ off_col, const int* __restrict__ cnt_col,
                            const float* __restrict__ dinv, const float* __restrict__ ys1,
                            const float* __restrict__ b1, const float* __restrict__ Wl1,
                            const float* __restrict__ bl1, const float* __restrict__ W2,
                            float* __restrict__ ys2, unsigned* __restrict__ masks){
  __shared__ float sWl1[D*D], sW2[D*D], sb1[D], sbl1[D];
  for (int i = threadIdx.x; i < D*D; i += blockDim.x){ sWl1[i] = Wl1[i]; sW2[i] = W2[i]; }
  if (threadIdx.x < D){ sb1[threadIdx.x] = b1[threadIdx.x]; sbl1[threadIdx.x] = bl1[threadIdx.x]; }
  __syncthreads();
  int t = blockIdx.x*blockDim.x + threadIdx.x;
  int n = t >> 4, k = t & 15;
  if (n >= NN) return;
  int base = off_col[n], cnt = cnt_col[n];
  float acc = 0.f;
  int i = 0;
  for (; i + 16 <= cnt; i += 16){
    int   se = col_src[base+i+k];   // coalesced: 16 lanes, 16 consecutive edges
    float we = col_w[base+i+k];
    #pragma unroll
    for (int j = 0; j < 16; j++){
      int   sj = __shfl(se, j, 16);
      float wj = __shfl(we, j, 16);
      acc += wj * ys1[sj*D+k];
    }
  }
  for (; i < cnt; i++)
    acc += col_w[base+i]*ys1[col_src[base+i]*D+k];
  float dv = dinv[n];
  float u1 = dv*(acc + ys1[n*D+k]) + sb1[k];
  float h1 = leakyf(u1);
  float u2 = sbl1[k];
  #pragma unroll
  for (int j = 0; j < D; j++) u2 += __shfl(h1, j, 16)*sWl1[j*D+k];
  float h2 = leakyf(u2);
  float yo = 0.f;
  #pragma unroll
  for (int j = 0; j < D; j++) yo += __shfl(h2, j, 16)*sW2[j*D+k];
  ys2[n*D+k] = dv*yo;
  unsigned mm = ((u1 >= 0.f) ? (1u<<k) : 0u) | ((u2 >= 0.f) ? (1u<<(16+k)) : 0u);
  mm |= (unsigned)__shfl_xor((int)mm, 8, 16);
  mm |= (unsigned)__shfl_xor((int)mm, 4, 16);
  mm |= (unsigned)__shfl_xor((int)mm, 2, 16);
  mm |= (unsigned)__shfl_xor((int)mm, 1, 16);
  if (k == 0) masks[n] = mm;
}

// conv2 gather (16-edge blocks) + head + energy + head backward: ds3, gdiag_s
__global__ void k_conv2_out(const int* __restrict__ col_src, const float* __restrict__ col_w,
                            const int* __restrict__ off_col, const int* __restrict__ cnt_col,
                            const float* __restrict__ dinv, const float* __restrict__ ys2,
                            const int* __restrict__ batch,
                            const float* __restrict__ b2, const float* __restrict__ Wl2,
                            const float* __restrict__ bl2, const float* __restrict__ Wl3,
                            const float* __restrict__ bl3,
                            float* __restrict__ Eout, float* __restrict__ ds3,
                            float* __restrict__ gdiag){
  __shared__ float sWl2[D*4], sb2[D], sbl2[4], sWl3[4], sbl3s;
  if (threadIdx.x < D*4) sWl2[threadIdx.x] = Wl2[threadIdx.x];
  if (threadIdx.x < D) sb2[threadIdx.x] = b2[threadIdx.x];
  if (threadIdx.x < 4){ sbl2[threadIdx.x] = bl2[threadIdx.x]; sWl3[threadIdx.x] = Wl3[threadIdx.x]; }
  if (threadIdx.x == 0) sbl3s = bl3[0];
  __syncthreads();
  int t = blockIdx.x*blockDim.x + threadIdx.x;
  int n = t >> 4, k = t & 15;
  if (n >= NN) return;
  int base = off_col[n], cnt = cnt_col[n];
  float acc = 0.f;
  int i = 0;
  for (; i + 16 <= cnt; i += 16){
    int   se = col_src[base+i+k];
    float we = col_w[base+i+k];
    #pragma unroll
    for (int j = 0; j < 16; j++){
      int   sj = __shfl(se, j, 16);
      float wj = __shfl(we, j, 16);
      acc += wj * ys2[sj*D+k];
    }
  }
  for (; i < cnt; i++)
    acc += col_w[base+i]*ys2[col_src[base+i]*D+k];
  float dv = dinv[n];
  float ysk = ys2[n*D+k];
  float u3 = dv*(acc + ysk) + sb2[k];
  float h3 = leakyf(u3);
  float u40 = sbl2[0], u41 = sbl2[1], u42 = sbl2[2], u43 = sbl2[3];
  #pragma unroll
  for (int j = 0; j < D; j++){
    float hj = __shfl(h3, j, 16);
    u40 += hj*sWl2[j*4+0]; u41 += hj*sWl2[j*4+1];
    u42 += hj*sWl2[j*4+2]; u43 += hj*sWl2[j*4+3];
  }
  float h40 = leakyf(u40), h41 = leakyf(u41), h42 = leakyf(u42), h43 = leakyf(u43);
  float u5 = sbl3s + h40*sWl3[0] + h41*sWl3[1] + h42*sWl3[2] + h43*sWl3[3];
  float h5 = leakyf(u5);
  if (k == 0) atomicAdd(&Eout[batch[n]], h5);
  float du5 = dleakyf(u5);
  float d40 = du5*sWl3[0]*dleakyf(u40);
  float d41 = du5*sWl3[1]*dleakyf(u41);
  float d42 = du5*sWl3[2]*dleakyf(u42);
  float d43 = du5*sWl3[3]*dleakyf(u43);
  float g = d40*sWl2[k*4+0] + d41*sWl2[k*4+1] + d42*sWl2[k*4+2] + d43*sWl2[k*4+3];
  float d3 = g*dleakyf(u3);
  ds3[n*D+k] = dv*d3;
  float gd = red16(d3*ysk);          // gdiag_s = dv * (du3 . y2)
  if (k == 0) gdiag[n] = gd;
}

// ---- backward -----------------------------------------------------------
// FUSED row pass 2 + node mid chain. 16-edge blocks; gn stored coalesced.
__global__ void k_bwd2mid(const int* __restrict__ row_dst, const float* __restrict__ row_w,
                          const int* __restrict__ off_row, const int* __restrict__ cnt_row,
                          const float* __restrict__ dinv, const float* __restrict__ ys1,
                          const float* __restrict__ ys2, const float* __restrict__ ds3,
                          const unsigned* __restrict__ masks,
                          const float* __restrict__ W2, const float* __restrict__ Wl1,
                          float* __restrict__ gn_row, float* __restrict__ ds1,
                          float* __restrict__ gdiag){
  __shared__ float sW2[D*D], sWl1[D*D];
  for (int i = threadIdx.x; i < D*D; i += blockDim.x){ sW2[i] = W2[i]; sWl1[i] = Wl1[i]; }
  __syncthreads();
  int t = blockIdx.x*blockDim.x + threadIdx.x;
  int n = t >> 4, k = t & 15;
  if (n >= NN) return;
  int base = off_row[n], cnt = cnt_row[n];
  float ysk = ys2[n*D+k];
  float gacc = 0.f;
  int i = 0;
  for (; i + 16 <= cnt; i += 16){
    int   ce = row_dst[base+i+k];
    float we = row_w[base+i+k];
    float myg = 0.f;
    #pragma unroll
    for (int j = 0; j < 16; j++){
      int   cj = __shfl(ce, j, 16);
      float wj = __shfl(we, j, 16);
      float dval = ds3[cj*D+k];
      gacc += wj*dval;
      float p = red16(dval*ysk);
      if (j == k) myg = p;
    }
    gn_row[base+i+k] = myg;          // coalesced store
  }
  for (; i < cnt; i++){
    int c = row_dst[base+i];
    float dval = ds3[c*D+k];
    gacc += row_w[base+i]*dval;
    float p = red16(dval*ysk);
    if (k == 0) gn_row[base+i] = p;
  }
  float dv = dinv[n];
  unsigned m = masks[n];
  float gy = dv*gacc + dv*ds3[n*D+k];      // gy2 + d2*du3
  float du2 = 0.f;
  #pragma unroll
  for (int j = 0; j < D; j++) du2 += __shfl(gy, j, 16)*sW2[k*D+j];
  du2 *= ((m>>(16+k))&1u) ? 1.0f : SLOPE;
  float du1 = 0.f;
  #pragma unroll
  for (int j = 0; j < D; j++) du1 += __shfl(du2, j, 16)*sWl1[k*D+j];
  du1 *= ((m>>k)&1u) ? 1.0f : SLOPE;
  float gd = red16(du1*ys1[n*D+k]);        // adds dv*(du1 . y1)
  if (k == 0) gdiag[n] += gd;
  ds1[n*D+k] = dv*du1;
}

// row pass 1: 16-edge blocks; gn_row += ds1[c].ys1[n]; gdinv_row = sum gn*w
__global__ void k_bwd1row(const int* __restrict__ row_dst, const float* __restrict__ row_w,
                          const int* __restrict__ off_row, const int* __restrict__ cnt_row,
                          const float* __restrict__ ys1, const float* __restrict__ ds1,
                          float* __restrict__ gn_row, float* __restrict__ gdinv_row){
  int t = blockIdx.x*blockDim.x + threadIdx.x;
  int n = t >> 4, k = t & 15;
  if (n >= NN) return;
  int base = off_row[n], cnt = cnt_row[n];
  float ysk = ys1[n*D+k];
  float gdr = 0.f;
  int i = 0;
  for (; i + 16 <= cnt; i += 16){
    int   ce = row_dst[base+i+k];
    float we = row_w[base+i+k];
    float gold = gn_row[base+i+k];   // coalesced read
    float myg = 0.f;
    #pragma unroll
    for (int j = 0; j < 16; j++){
      int   cj = __shfl(ce, j, 16);
      float wj = __shfl(we, j, 16);
      float dval = ds1[cj*D+k];
      float p = red16(dval*ysk);
      float gj = __shfl(gold, j, 16) + p;
      if (j == k) myg = gj;
      gdr += gj*wj;
    }
    gn_row[base+i+k] = myg;          // coalesced store
  }
  for (; i < cnt; i++){
    int c = row_dst[base+i];
    float dval = ds1[c*D+k];
    float p = red16(dval*ysk);
    float g = gn_row[base+i] + p;
    if (k == 0) gn_row[base+i] = g;
    gdr += g*row_w[base+i];
  }
  if (k == 0) gdinv_row[n] = gdr;
}

// col pass: gns_col copy (contiguous write), gdeg, packed node table (pos, gdeg)
__global__ void k_gdeg(const int* __restrict__ col_rp, const float* __restrict__ col_w,
                       const int* __restrict__ off_col, const int* __restrict__ cnt_col,
                       const float* __restrict__ gn_row, const float* __restrict__ gdinv_row,
                       const float* __restrict__ gdiag, const float* __restrict__ dinv,
                       const float4* __restrict__ pos4,
                       float* __restrict__ gns_col, float4* __restrict__ pn4){
  int t = blockIdx.x*blockDim.x + threadIdx.x;
  int n = t >> 4, k = t & 15;
  if (n >= NN) return;
  int base = off_col[n], cnt = cnt_col[n];
  float gc = 0.f;
  for (int i = k; i < cnt; i += 16){
    float g = gn_row[col_rp[base+i]];
    gc += g*col_w[base+i];
    gns_col[base+i] = g;
  }
  gc = red16(gc);
  if (k == 0){
    float dv = dinv[n];
    float arg = (gdinv_row[n] + gc)/dv + 2.0f*gdiag[n];  // gdiag holds dv*gdiag_true
    float gd = -0.5f*dv*dv*dv*arg;
    float4 p = pos4[n];
    pn4[n] = make_float4(p.x, p.y, p.z, gd);
  }
}

// force gather: coef = (gns + gdeg[col-node])/w, both directions
__global__ void k_force(const int* __restrict__ row_dst, const float* __restrict__ row_w,
                        const int* __restrict__ off_row, const int* __restrict__ cnt_row,
                        const int* __restrict__ col_src, const float* __restrict__ col_w,
                        const int* __restrict__ off_col, const int* __restrict__ cnt_col,
                        const float* __restrict__ gn_row, const float* __restrict__ gns_col,
                        const float4* __restrict__ pn4, float* __restrict__ F){
  int t = blockIdx.x*blockDim.x + threadIdx.x;
  int n = t >> 4, k = t & 15;
  if (n >= NN) return;
  float4 pn = pn4[n];
  float fx = 0.f, fy = 0.f, fz = 0.f;
  int base = off_row[n], cnt = cnt_row[n];
  for (int i = k; i < cnt; i += 16){
    int c = row_dst[base+i];
    float g = gn_row[base+i];
    float4 pc = pn4[c];
    float coef = (g + pc.w)/row_w[base+i];
    fx -= coef*(pn.x-pc.x); fy -= coef*(pn.y-pc.y); fz -= coef*(pn.z-pc.z);
  }
  base = off_col[n]; cnt = cnt_col[n];
  for (int i = k; i < cnt; i += 16){
    int r = col_src[base+i];
    float g = gns_col[base+i];
    float4 pr = pn4[r];
    float coef = (g + pn.w)/col_w[base+i];
    fx += coef*(pr.x-pn.x); fy += coef*(pr.y-pn.y); fz += coef*(pr.z-pn.z);
  }
  fx = red16(fx); fy = red16(fy); fz = red16(fz);
  if (k == 0){ F[3*n+0] = fx; F[3*n+1] = fy; F[3*n+2] = fz; }
}

extern "C" void kernel_launch(void* const* d_in, const int* in_sizes, int n_in,
                              void* d_out, int out_size, void* d_ws, size_t ws_size,
                              hipStream_t stream){
  const float* pos = (const float*)d_in[0];
  const float* emb = (const float*)d_in[1];
  const float* W1  = (const float*)d_in[2];
  const float* b1  = (const float*)d_in[3];
  const float* Wl1 = (const float*)d_in[4];
  const float* bl1 = (const float*)d_in[5];
  const float* W2  = (const float*)d_in[6];
  const float* b2  = (const float*)d_in[7];
  const float* Wl2 = (const float*)d_in[8];
  const float* bl2 = (const float*)d_in[9];
  const float* Wl3 = (const float*)d_in[10];
  const float* bl3 = (const float*)d_in[11];
  const int* z     = (const int*)d_in[12];
  const int* ei    = (const int*)d_in[13];
  const int* batch = (const int*)d_in[14];

  // workspace: ~78N + 6E words ~= 108 MB
  char* base = (char*)d_ws;
  size_t o = 0;
  auto alloc = [&](size_t words){ o = (o + 3) & ~(size_t)3; void* p = base + o*4; o += words; return p; };
  int*   cnt_row   = (int*)alloc(NN);
  int*   cnt_col   = (int*)alloc(NN);
  int*   off_row   = (int*)alloc(NN);
  int*   off_col   = (int*)alloc(NN);
  int*   cur_row   = (int*)alloc(NN);
  int*   cur_col   = (int*)alloc(NN);
  int*   bsum      = (int*)alloc(1024);
  float* dinv      = (float*)alloc(NN);
  float* gdiag     = (float*)alloc(NN);
  float* gdinv_row = (float*)alloc(NN);
  unsigned* masks  = (unsigned*)alloc(NN);
  float4* pos4     = (float4*)alloc(4*NN);
  float* ys1       = (float*)alloc(16*NN);
  float* ys2       = (float*)alloc(16*NN);
  float* ds3       = (float*)alloc(16*NN);
  float* ds1       = (float*)alloc(16*NN);
  int*   row_dst   = (int*)alloc(NE);
  float* row_w     = (float*)alloc(NE);
  int*   col_src   = (int*)alloc(NE);
  int*   col_rp    = (int*)alloc(NE);
  float* col_w     = (float*)alloc(NE);
  float* gn_row    = (float*)alloc(NE);
  // aliases (lifetimes disjoint): gns_col over ys1+ys2 (E == 32N, both dead
  // after k_bwd1row); pn4 over ds3 (dead after k_bwd2mid)
  float*  gns_col = ys1;
  float4* pn4     = (float4*)ds3;

  float* Eout = (float*)d_out;
  float* F = Eout + NG;

  int nbN   = (NN + BT - 1)/BT;        // 391
  int nbE   = (NE + BT - 1)/BT;
  int nbE4  = (NE/4 + BT - 1)/BT;
  int nbN16 = (NN*16 + BT - 1)/BT;     // 6250

  hipMemsetAsync(cnt_row, 0, 2*(size_t)NN*4, stream);
  hipMemsetAsync(Eout, 0, (size_t)NG*4, stream);

  k_pos4<<<nbN, BT, 0, stream>>>(pos, pos4);

  // CSR build
  k_count<<<nbE4, BT, 0, stream>>>(ei, cnt_row, cnt_col);
  k_blocksum<<<dim3(nbN,2), BT, 0, stream>>>(cnt_row, cnt_col, bsum);
  k_scan_bsum<<<dim3(1,2), 512, 0, stream>>>(bsum, nbN);
  k_offsets<<<dim3(nbN,2), BT, 0, stream>>>(cnt_row, cnt_col, bsum,
                                            off_row, off_col, cur_row, cur_col);
  k_place<<<nbE, BT, 0, stream>>>(ei, pos4, cur_row, cur_col,
                                  row_dst, row_w, col_src, col_rp, col_w);

  // forward
  k_dinv_y1<<<nbN16, BT, 0, stream>>>(col_w, off_col, cnt_col, emb, z, W1, dinv, ys1);
  k_conv1_mid<<<nbN16, BT, 0, stream>>>(col_src, col_w, off_col, cnt_col, dinv, ys1,
                                        b1, Wl1, bl1, W2, ys2, masks);
  k_conv2_out<<<nbN16, BT, 0, stream>>>(col_src, col_w, off_col, cnt_col, dinv, ys2,
                                        batch, b2, Wl2, bl2, Wl3, bl3, Eout, ds3, gdiag);

  // backward
  k_bwd2mid<<<nbN16, BT, 0, stream>>>(row_dst, row_w, off_row, cnt_row, dinv, ys1, ys2,
                                      ds3, masks, W2, Wl1, gn_row, ds1, gdiag);
  k_bwd1row<<<nbN16, BT, 0, stream>>>(row_dst, row_w, off_row, cnt_row, ys1, ds1,
                                      gn_row, gdinv_row);
  k_gdeg<<<nbN16, BT, 0, stream>>>(col_rp, col_w, off_col, cnt_col, gn_row, gdinv_row,
                                   gdiag, dinv, pos4, gns_col, pn4);
  k_force<<<nbN16, BT, 0, stream>>>(row_dst, row_w, off_row, cnt_row,
                                    col_src, col_w, off_col, cnt_col,
                                    gn_row, gns_col, pn4, F);
}

// Round 7
// 945.060 us; speedup vs baseline: 2.5559x; 1.2251x over previous
//
#include <hip/hip_runtime.h>
#include <math.h>

#define NN 100000
#define NE 3200000
#define NG 512
#define D 16
#define SLOPE 0.01f
#define BT 256
#define CAP 80   // padded-CSR slots per node (mean deg 32, exp. max ~60)

__device__ __forceinline__ float leakyf(float x){ return x >= 0.0f ? x : SLOPE*x; }
__device__ __forceinline__ float dleakyf(float x){ return x >= 0.0f ? 1.0f : SLOPE; }

__device__ __forceinline__ float red16(float v){
  v += __shfl_xor(v, 8, 16);
  v += __shfl_xor(v, 4, 16);
  v += __shfl_xor(v, 2, 16);
  v += __shfl_xor(v, 1, 16);
  return v;
}

// pos (N,3) -> pos4 (N,4) aligned 16B rows
__global__ void k_pos4(const float* __restrict__ pos, float4* __restrict__ pos4){
  int n = blockIdx.x*blockDim.x + threadIdx.x;
  if (n >= NN) return;
  pos4[n] = make_float4(pos[3*n+0], pos[3*n+1], pos[3*n+2], 0.0f);
}

// ---- CSR build, compact path (count + scan + place) ----------------------
__global__ void k_count(const int* __restrict__ ei, int* __restrict__ cnt_row,
                        int* __restrict__ cnt_col){
  int t = blockIdx.x*blockDim.x + threadIdx.x;
  if (t >= NE/4) return;
  int4 r4 = ((const int4*)ei)[t];
  int4 c4 = ((const int4*)(ei + NE))[t];
  atomicAdd(&cnt_row[r4.x], 1); atomicAdd(&cnt_row[r4.y], 1);
  atomicAdd(&cnt_row[r4.z], 1); atomicAdd(&cnt_row[r4.w], 1);
  atomicAdd(&cnt_col[c4.x], 1); atomicAdd(&cnt_col[c4.y], 1);
  atomicAdd(&cnt_col[c4.z], 1); atomicAdd(&cnt_col[c4.w], 1);
}

__global__ void k_blocksum(const int* __restrict__ cnt_row, const int* __restrict__ cnt_col,
                           int* __restrict__ bsum){
  const int* src = blockIdx.y ? cnt_col : cnt_row;
  __shared__ int s[BT];
  int i = blockIdx.x*BT + threadIdx.x;
  s[threadIdx.x] = (i < NN) ? src[i] : 0;
  __syncthreads();
  for (int off = BT/2; off > 0; off >>= 1){
    if (threadIdx.x < off) s[threadIdx.x] += s[threadIdx.x+off];
    __syncthreads();
  }
  if (threadIdx.x == 0) bsum[blockIdx.y*512 + blockIdx.x] = s[0];
}

__global__ void k_scan_bsum(int* __restrict__ bsum, int nb){
  int* b = bsum + blockIdx.y*512;
  __shared__ int s0[512], s1[512];
  int tid = threadIdx.x;
  int v = (tid < nb) ? b[tid] : 0;
  s0[tid] = v; __syncthreads();
  int rd = 0;
  for (int off = 1; off < 512; off <<= 1){
    int x = rd ? s1[tid] : s0[tid];
    if (tid >= off) x += rd ? s1[tid-off] : s0[tid-off];
    if (rd) s0[tid] = x; else s1[tid] = x;
    __syncthreads();
    rd ^= 1;
  }
  int incl = rd ? s1[tid] : s0[tid];
  if (tid < nb) b[tid] = incl - v;
}

__global__ void k_offsets(const int* __restrict__ cnt_row, const int* __restrict__ cnt_col,
                          const int* __restrict__ bsum,
                          int* __restrict__ off_row, int* __restrict__ off_col,
                          int* __restrict__ cur_row, int* __restrict__ cur_col){
  const int* src  = blockIdx.y ? cnt_col : cnt_row;
  int* offd = blockIdx.y ? off_col : off_row;
  int* curd = blockIdx.y ? cur_col : cur_row;
  __shared__ int s0[BT], s1[BT];
  int tid = threadIdx.x;
  int i = blockIdx.x*BT + tid;
  int v = (i < NN) ? src[i] : 0;
  s0[tid] = v; __syncthreads();
  int rd = 0;
  for (int off = 1; off < BT; off <<= 1){
    int x = rd ? s1[tid] : s0[tid];
    if (tid >= off) x += rd ? s1[tid-off] : s0[tid-off];
    if (rd) s0[tid] = x; else s1[tid] = x;
    __syncthreads();
    rd ^= 1;
  }
  int incl = rd ? s1[tid] : s0[tid];
  if (i < NN){
    int o = bsum[blockIdx.y*512 + blockIdx.x] + incl - v;
    offd[i] = o; curd[i] = o;
  }
}

// SoA scattered 4B stores (measured fastest layout, r2 vs r3)
__global__ void k_place(const int* __restrict__ ei, const float4* __restrict__ pos4,
                        int* __restrict__ cur_row, int* __restrict__ cur_col,
                        int* __restrict__ row_dst, float* __restrict__ row_w,
                        int* __restrict__ col_src, int* __restrict__ col_rp,
                        float* __restrict__ col_w){
  int e = blockIdx.x*blockDim.x + threadIdx.x;
  if (e >= NE) return;
  int r = ei[e], c = ei[NE+e];
  float4 pr = pos4[r], pc = pos4[c];
  float dx = pr.x-pc.x, dy = pr.y-pc.y, dz = pr.z-pc.z;
  float w = sqrtf(dx*dx+dy*dy+dz*dz);
  int p = atomicAdd(&cur_row[r], 1);
  int q = atomicAdd(&cur_col[c], 1);
  row_dst[p] = c; row_w[p] = w;
  col_src[q] = r; col_rp[q] = p; col_w[q] = w;
}

// ---- CSR build, padded path (no count/scan; base = n*CAP) ----------------
__global__ void k_offpad(int* __restrict__ off_row, int* __restrict__ off_col){
  int n = blockIdx.x*blockDim.x + threadIdx.x;
  if (n >= NN) return;
  off_row[n] = n*CAP; off_col[n] = n*CAP;
}

__global__ void k_place_pad(const int* __restrict__ ei, const float4* __restrict__ pos4,
                            int* __restrict__ cnt_row, int* __restrict__ cnt_col,
                            int* __restrict__ row_dst, float* __restrict__ row_w,
                            int* __restrict__ col_src, int* __restrict__ col_rp,
                            float* __restrict__ col_w){
  int e = blockIdx.x*blockDim.x + threadIdx.x;
  if (e >= NE) return;
  int r = ei[e], c = ei[NE+e];
  float4 pr = pos4[r], pc = pos4[c];
  float dx = pr.x-pc.x, dy = pr.y-pc.y, dz = pr.z-pc.z;
  float w = sqrtf(dx*dx+dy*dy+dz*dz);
  int p = r*CAP + atomicAdd(&cnt_row[r], 1);
  int q = c*CAP + atomicAdd(&cnt_col[c], 1);
  row_dst[p] = c; row_w[p] = w;
  col_src[q] = r; col_rp[q] = p; col_w[q] = w;
}

// ---- forward ------------------------------------------------------------
__global__ void k_dinv_y1(const float* __restrict__ col_w, const int* __restrict__ off_col,
                          const int* __restrict__ cnt_col,
                          const float* __restrict__ emb, const int* __restrict__ z,
                          const float* __restrict__ W1,
                          float* __restrict__ dinv, float* __restrict__ ys1){
  __shared__ float sW[D*D];
  for (int i = threadIdx.x; i < D*D; i += blockDim.x) sW[i] = W1[i];
  __syncthreads();
  int t = blockIdx.x*blockDim.x + threadIdx.x;
  int n = t >> 4, k = t & 15;
  if (n >= NN) return;
  int base = off_col[n], cnt = cnt_col[n];
  float s = 0.f;
  for (int i = k; i < cnt; i += 16) s += col_w[base+i];
  s = red16(s);
  float dv = 1.0f / sqrtf(1.0f + s);
  if (k == 0) dinv[n] = dv;
  float h = emb[z[n]*D + k];
  float acc = 0.f;
  #pragma unroll
  for (int j = 0; j < D; j++) acc += __shfl(h, j, 16)*sW[j*D+k];
  ys1[n*D+k] = dv*acc;
}

// conv1 gather (16-edge blocks: coalesced src/w loads + shfl broadcast) + MLP mid
__global__ void k_conv1_mid(const int* __restrict__ col_src, const float* __restrict__ col_w,
                            const int* __restrict__ off_col, const int* __restrict__ cnt_col,
                            const float* __restrict__ dinv, const float* __restrict__ ys1,
                            const float* __restrict__ b1, const float* __restrict__ Wl1,
                            const float* __restrict__ bl1, const float* __restrict__ W2,
                            float* __restrict__ ys2, unsigned* __restrict__ masks){
  __shared__ float sWl1[D*D], sW2[D*D], sb1[D], sbl1[D];
  for (int i = threadIdx.x; i < D*D; i += blockDim.x){ sWl1[i] = Wl1[i]; sW2[i] = W2[i]; }
  if (threadIdx.x < D){ sb1[threadIdx.x] = b1[threadIdx.x]; sbl1[threadIdx.x] = bl1[threadIdx.x]; }
  __syncthreads();
  int t = blockIdx.x*blockDim.x + threadIdx.x;
  int n = t >> 4, k = t & 15;
  if (n >= NN) return;
  int base = off_col[n], cnt = cnt_col[n];
  float acc = 0.f;
  int i = 0;
  for (; i + 16 <= cnt; i += 16){
    int   se = col_src[base+i+k];   // coalesced: 16 lanes, 16 consecutive edges
    float we = col_w[base+i+k];
    #pragma unroll
    for (int j = 0; j < 16; j++){
      int   sj = __shfl(se, j, 16);
      float wj = __shfl(we, j, 16);
      acc += wj * ys1[sj*D+k];
    }
  }
  for (; i < cnt; i++)
    acc += col_w[base+i]*ys1[col_src[base+i]*D+k];
  float dv = dinv[n];
  float u1 = dv*(acc + ys1[n*D+k]) + sb1[k];
  float h1 = leakyf(u1);
  float u2 = sbl1[k];
  #pragma unroll
  for (int j = 0; j < D; j++) u2 += __shfl(h1, j, 16)*sWl1[j*D+k];
  float h2 = leakyf(u2);
  float yo = 0.f;
  #pragma unroll
  for (int j = 0; j < D; j++) yo += __shfl(h2, j, 16)*sW2[j*D+k];
  ys2[n*D+k] = dv*yo;
  unsigned mm = ((u1 >= 0.f) ? (1u<<k) : 0u) | ((u2 >= 0.f) ? (1u<<(16+k)) : 0u);
  mm |= (unsigned)__shfl_xor((int)mm, 8, 16);
  mm |= (unsigned)__shfl_xor((int)mm, 4, 16);
  mm |= (unsigned)__shfl_xor((int)mm, 2, 16);
  mm |= (unsigned)__shfl_xor((int)mm, 1, 16);
  if (k == 0) masks[n] = mm;
}

// conv2 gather (16-edge blocks) + head + energy + head backward: ds3, gdiag_s
__global__ void k_conv2_out(const int* __restrict__ col_src, const float* __restrict__ col_w,
                            const int* __restrict__ off_col, const int* __restrict__ cnt_col,
                            const float* __restrict__ dinv, const float* __restrict__ ys2,
                            const int* __restrict__ batch,
                            const float* __restrict__ b2, const float* __restrict__ Wl2,
                            const float* __restrict__ bl2, const float* __restrict__ Wl3,
                            const float* __restrict__ bl3,
                            float* __restrict__ Eout, float* __restrict__ ds3,
                            float* __restrict__ gdiag){
  __shared__ float sWl2[D*4], sb2[D], sbl2[4], sWl3[4], sbl3s;
  if (threadIdx.x < D*4) sWl2[threadIdx.x] = Wl2[threadIdx.x];
  if (threadIdx.x < D) sb2[threadIdx.x] = b2[threadIdx.x];
  if (threadIdx.x < 4){ sbl2[threadIdx.x] = bl2[threadIdx.x]; sWl3[threadIdx.x] = Wl3[threadIdx.x]; }
  if (threadIdx.x == 0) sbl3s = bl3[0];
  __syncthreads();
  int t = blockIdx.x*blockDim.x + threadIdx.x;
  int n = t >> 4, k = t & 15;
  if (n >= NN) return;
  int base = off_col[n], cnt = cnt_col[n];
  float acc = 0.f;
  int i = 0;
  for (; i + 16 <= cnt; i += 16){
    int   se = col_src[base+i+k];
    float we = col_w[base+i+k];
    #pragma unroll
    for (int j = 0; j < 16; j++){
      int   sj = __shfl(se, j, 16);
      float wj = __shfl(we, j, 16);
      acc += wj * ys2[sj*D+k];
    }
  }
  for (; i < cnt; i++)
    acc += col_w[base+i]*ys2[col_src[base+i]*D+k];
  float dv = dinv[n];
  float ysk = ys2[n*D+k];
  float u3 = dv*(acc + ysk) + sb2[k];
  float h3 = leakyf(u3);
  float u40 = sbl2[0], u41 = sbl2[1], u42 = sbl2[2], u43 = sbl2[3];
  #pragma unroll
  for (int j = 0; j < D; j++){
    float hj = __shfl(h3, j, 16);
    u40 += hj*sWl2[j*4+0]; u41 += hj*sWl2[j*4+1];
    u42 += hj*sWl2[j*4+2]; u43 += hj*sWl2[j*4+3];
  }
  float h40 = leakyf(u40), h41 = leakyf(u41), h42 = leakyf(u42), h43 = leakyf(u43);
  float u5 = sbl3s + h40*sWl3[0] + h41*sWl3[1] + h42*sWl3[2] + h43*sWl3[3];
  float h5 = leakyf(u5);
  if (k == 0) atomicAdd(&Eout[batch[n]], h5);
  float du5 = dleakyf(u5);
  float d40 = du5*sWl3[0]*dleakyf(u40);
  float d41 = du5*sWl3[1]*dleakyf(u41);
  float d42 = du5*sWl3[2]*dleakyf(u42);
  float d43 = du5*sWl3[3]*dleakyf(u43);
  float g = d40*sWl2[k*4+0] + d41*sWl2[k*4+1] + d42*sWl2[k*4+2] + d43*sWl2[k*4+3];
  float d3 = g*dleakyf(u3);
  ds3[n*D+k] = dv*d3;
  float gd = red16(d3*ysk);          // gdiag_s = dv * (du3 . y2)
  if (k == 0) gdiag[n] = gd;
}

// ---- backward -----------------------------------------------------------
// FUSED row pass 2 + node mid chain. 16-edge blocks; gn stored coalesced.
__global__ void k_bwd2mid(const int* __restrict__ row_dst, const float* __restrict__ row_w,
                          const int* __restrict__ off_row, const int* __restrict__ cnt_row,
                          const float* __restrict__ dinv, const float* __restrict__ ys1,
                          const float* __restrict__ ys2, const float* __restrict__ ds3,
                          const unsigned* __restrict__ masks,
                          const float* __restrict__ W2, const float* __restrict__ Wl1,
                          float* __restrict__ gn_row, float* __restrict__ ds1,
                          float* __restrict__ gdiag){
  __shared__ float sW2[D*D], sWl1[D*D];
  for (int i = threadIdx.x; i < D*D; i += blockDim.x){ sW2[i] = W2[i]; sWl1[i] = Wl1[i]; }
  __syncthreads();
  int t = blockIdx.x*blockDim.x + threadIdx.x;
  int n = t >> 4, k = t & 15;
  if (n >= NN) return;
  int base = off_row[n], cnt = cnt_row[n];
  float ysk = ys2[n*D+k];
  float gacc = 0.f;
  int i = 0;
  for (; i + 16 <= cnt; i += 16){
    int   ce = row_dst[base+i+k];
    float we = row_w[base+i+k];
    float myg = 0.f;
    #pragma unroll
    for (int j = 0; j < 16; j++){
      int   cj = __shfl(ce, j, 16);
      float wj = __shfl(we, j, 16);
      float dval = ds3[cj*D+k];
      gacc += wj*dval;
      float p = red16(dval*ysk);
      if (j == k) myg = p;
    }
    gn_row[base+i+k] = myg;          // coalesced store
  }
  for (; i < cnt; i++){
    int c = row_dst[base+i];
    float dval = ds3[c*D+k];
    gacc += row_w[base+i]*dval;
    float p = red16(dval*ysk);
    if (k == 0) gn_row[base+i] = p;
  }
  float dv = dinv[n];
  unsigned m = masks[n];
  float gy = dv*gacc + dv*ds3[n*D+k];      // gy2 + d2*du3
  float du2 = 0.f;
  #pragma unroll
  for (int j = 0; j < D; j++) du2 += __shfl(gy, j, 16)*sW2[k*D+j];
  du2 *= ((m>>(16+k))&1u) ? 1.0f : SLOPE;
  float du1 = 0.f;
  #pragma unroll
  for (int j = 0; j < D; j++) du1 += __shfl(du2, j, 16)*sWl1[k*D+j];
  du1 *= ((m>>k)&1u) ? 1.0f : SLOPE;
  float gd = red16(du1*ys1[n*D+k]);        // adds dv*(du1 . y1)
  if (k == 0) gdiag[n] += gd;
  ds1[n*D+k] = dv*du1;
}

// row pass 1: 16-edge blocks; gn_row += ds1[c].ys1[n]; gdinv_row = sum gn*w
__global__ void k_bwd1row(const int* __restrict__ row_dst, const float* __restrict__ row_w,
                          const int* __restrict__ off_row, const int* __restrict__ cnt_row,
                          const float* __restrict__ ys1, const float* __restrict__ ds1,
                          float* __restrict__ gn_row, float* __restrict__ gdinv_row){
  int t = blockIdx.x*blockDim.x + threadIdx.x;
  int n = t >> 4, k = t & 15;
  if (n >= NN) return;
  int base = off_row[n], cnt = cnt_row[n];
  float ysk = ys1[n*D+k];
  float gdr = 0.f;
  int i = 0;
  for (; i + 16 <= cnt; i += 16){
    int   ce = row_dst[base+i+k];
    float we = row_w[base+i+k];
    float gold = gn_row[base+i+k];   // coalesced read
    float myg = 0.f;
    #pragma unroll
    for (int j = 0; j < 16; j++){
      int   cj = __shfl(ce, j, 16);
      float wj = __shfl(we, j, 16);
      float dval = ds1[cj*D+k];
      float p = red16(dval*ysk);
      float gj = __shfl(gold, j, 16) + p;
      if (j == k) myg = gj;
      gdr += gj*wj;
    }
    gn_row[base+i+k] = myg;          // coalesced store
  }
  for (; i < cnt; i++){
    int c = row_dst[base+i];
    float dval = ds1[c*D+k];
    float p = red16(dval*ysk);
    float g = gn_row[base+i] + p;
    if (k == 0) gn_row[base+i] = g;
    gdr += g*row_w[base+i];
  }
  if (k == 0) gdinv_row[n] = gdr;
}

// col pass: gns_col copy (contiguous write), gdeg, packed node table (pos, gdeg)
__global__ void k_gdeg(const int* __restrict__ col_rp, const float* __restrict__ col_w,
                       const int* __restrict__ off_col, const int* __restrict__ cnt_col,
                       const float* __restrict__ gn_row, const float* __restrict__ gdinv_row,
                       const float* __restrict__ gdiag, const float* __restrict__ dinv,
                       const float4* __restrict__ pos4,
                       float* __restrict__ gns_col, float4* __restrict__ pn4){
  int t = blockIdx.x*blockDim.x + threadIdx.x;
  int n = t >> 4, k = t & 15;
  if (n >= NN) return;
  int base = off_col[n], cnt = cnt_col[n];
  float gc = 0.f;
  for (int i = k; i < cnt; i += 16){
    float g = gn_row[col_rp[base+i]];
    gc += g*col_w[base+i];
    gns_col[base+i] = g;
  }
  gc = red16(gc);
  if (k == 0){
    float dv = dinv[n];
    float arg = (gdinv_row[n] + gc)/dv + 2.0f*gdiag[n];  // gdiag holds dv*gdiag_true
    float gd = -0.5f*dv*dv*dv*arg;
    float4 p = pos4[n];
    pn4[n] = make_float4(p.x, p.y, p.z, gd);
  }
}

// force gather: coef = (gns + gdeg[col-node])/w, both directions
__global__ void k_force(const int* __restrict__ row_dst, const float* __restrict__ row_w,
                        const int* __restrict__ off_row, const int* __restrict__ cnt_row,
                        const int* __restrict__ col_src, const float* __restrict__ col_w,
                        const int* __restrict__ off_col, const int* __restrict__ cnt_col,
                        const float* __restrict__ gn_row, const float* __restrict__ gns_col,
                        const float4* __restrict__ pn4, float* __restrict__ F){
  int t = blockIdx.x*blockDim.x + threadIdx.x;
  int n = t >> 4, k = t & 15;
  if (n >= NN) return;
  float4 pn = pn4[n];
  float fx = 0.f, fy = 0.f, fz = 0.f;
  int base = off_row[n], cnt = cnt_row[n];
  for (int i = k; i < cnt; i += 16){
    int c = row_dst[base+i];
    float g = gn_row[base+i];
    float4 pc = pn4[c];
    float coef = (g + pc.w)/row_w[base+i];
    fx -= coef*(pn.x-pc.x); fy -= coef*(pn.y-pc.y); fz -= coef*(pn.z-pc.z);
  }
  base = off_col[n]; cnt = cnt_col[n];
  for (int i = k; i < cnt; i += 16){
    int r = col_src[base+i];
    float g = gns_col[base+i];
    float4 pr = pn4[r];
    float coef = (g + pn.w)/col_w[base+i];
    fx += coef*(pr.x-pn.x); fy += coef*(pr.y-pn.y); fz += coef*(pr.z-pn.z);
  }
  fx = red16(fx); fy = red16(fy); fz = red16(fz);
  if (k == 0){ F[3*n+0] = fx; F[3*n+1] = fy; F[3*n+2] = fz; }
}

extern "C" void kernel_launch(void* const* d_in, const int* in_sizes, int n_in,
                              void* d_out, int out_size, void* d_ws, size_t ws_size,
                              hipStream_t stream){
  const float* pos = (const float*)d_in[0];
  const float* emb = (const float*)d_in[1];
  const float* W1  = (const float*)d_in[2];
  const float* b1  = (const float*)d_in[3];
  const float* Wl1 = (const float*)d_in[4];
  const float* bl1 = (const float*)d_in[5];
  const float* W2  = (const float*)d_in[6];
  const float* b2  = (const float*)d_in[7];
  const float* Wl2 = (const float*)d_in[8];
  const float* bl2 = (const float*)d_in[9];
  const float* Wl3 = (const float*)d_in[10];
  const float* bl3 = (const float*)d_in[11];
  const int* z     = (const int*)d_in[12];
  const int* ei    = (const int*)d_in[13];
  const int* batch = (const int*)d_in[14];

  // padded layout needs ~78N + 1024 + 7*CAP*N words (~255 MB); gate on ws_size
  size_t need_pad = 4ull*((size_t)78*NN + 1024 + 7ull*CAP*NN);
  bool padded = (ws_size >= need_pad);
  size_t ER = padded ? (size_t)CAP*NN : (size_t)NE;   // edge-array length

  char* base = (char*)d_ws;
  size_t o = 0;
  auto alloc = [&](size_t words){ o = (o + 15) & ~(size_t)15; void* p = base + o*4; o += words; return p; };
  int*   cnt_row   = (int*)alloc(NN);
  int*   cnt_col   = (int*)alloc(NN);
  int*   off_row   = (int*)alloc(NN);
  int*   off_col   = (int*)alloc(NN);
  int*   cur_row   = (int*)alloc(NN);
  int*   cur_col   = (int*)alloc(NN);
  int*   bsum      = (int*)alloc(1024);
  float* dinv      = (float*)alloc(NN);
  float* gdiag     = (float*)alloc(NN);
  float* gdinv_row = (float*)alloc(NN);
  unsigned* masks  = (unsigned*)alloc(NN);
  float4* pos4     = (float4*)alloc(4*NN);
  float* ys1       = (float*)alloc(16*NN);
  float* ys2       = (float*)alloc(16*NN);
  float* ds3       = (float*)alloc(16*NN);
  float* ds1       = (float*)alloc(16*NN);
  int*   row_dst   = (int*)alloc(ER);
  float* row_w     = (float*)alloc(ER);
  int*   col_src   = (int*)alloc(ER);
  int*   col_rp    = (int*)alloc(ER);
  float* col_w     = (float*)alloc(ER);
  float* gn_row    = (float*)alloc(ER);
  // gns_col: padded path allocates; compact path aliases ys1+ys2 (E == 32N,
  // both dead after k_bwd1row). pn4 aliases ds3 (dead after k_bwd2mid).
  float*  gns_col = padded ? (float*)alloc(ER) : ys1;
  float4* pn4     = (float4*)ds3;

  float* Eout = (float*)d_out;
  float* F = Eout + NG;

  int nbN   = (NN + BT - 1)/BT;        // 391
  int nbE   = (NE + BT - 1)/BT;
  int nbE4  = (NE/4 + BT - 1)/BT;
  int nbN16 = (NN*16 + BT - 1)/BT;     // 6250

  hipMemsetAsync(cnt_row, 0, 2*(size_t)NN*4, stream);
  hipMemsetAsync(Eout, 0, (size_t)NG*4, stream);

  k_pos4<<<nbN, BT, 0, stream>>>(pos, pos4);

  // CSR build
  if (padded){
    k_offpad<<<nbN, BT, 0, stream>>>(off_row, off_col);
    k_place_pad<<<nbE, BT, 0, stream>>>(ei, pos4, cnt_row, cnt_col,
                                        row_dst, row_w, col_src, col_rp, col_w);
  } else {
    k_count<<<nbE4, BT, 0, stream>>>(ei, cnt_row, cnt_col);
    k_blocksum<<<dim3(nbN,2), BT, 0, stream>>>(cnt_row, cnt_col, bsum);
    k_scan_bsum<<<dim3(1,2), 512, 0, stream>>>(bsum, nbN);
    k_offsets<<<dim3(nbN,2), BT, 0, stream>>>(cnt_row, cnt_col, bsum,
                                              off_row, off_col, cur_row, cur_col);
    k_place<<<nbE, BT, 0, stream>>>(ei, pos4, cur_row, cur_col,
                                    row_dst, row_w, col_src, col_rp, col_w);
  }

  // forward
  k_dinv_y1<<<nbN16, BT, 0, stream>>>(col_w, off_col, cnt_col, emb, z, W1, dinv, ys1);
  k_conv1_mid<<<nbN16, BT, 0, stream>>>(col_src, col_w, off_col, cnt_col, dinv, ys1,
                                        b1, Wl1, bl1, W2, ys2, masks);
  k_conv2_out<<<nbN16, BT, 0, stream>>>(col_src, col_w, off_col, cnt_col, dinv, ys2,
                                        batch, b2, Wl2, bl2, Wl3, bl3, Eout, ds3, gdiag);

  // backward
  k_bwd2mid<<<nbN16, BT, 0, stream>>>(row_dst, row_w, off_row, cnt_row, dinv, ys1, ys2,
                                      ds3, masks, W2, Wl1, gn_row, ds1, gdiag);
  k_bwd1row<<<nbN16, BT, 0, stream>>>(row_dst, row_w, off_row, cnt_row, ys1, ds1,
                                      gn_row, gdinv_row);
  k_gdeg<<<nbN16, BT, 0, stream>>>(col_rp, col_w, off_col, cnt_col, gn_row, gdinv_row,
                                   gdiag, dinv, pos4, gns_col, pn4);
  k_force<<<nbN16, BT, 0, stream>>>(row_dst, row_w, off_row, cnt_row,
                                    col_src, col_w, off_col, cnt_col,
                                    gn_row, gns_col, pn4, F);
}

// Round 8
// 920.563 us; speedup vs baseline: 2.6239x; 1.0266x over previous
//
#include <hip/hip_runtime.h>
#include <math.h>

#define NN 100000
#define NE 3200000
#define NG 512
#define D 16
#define SLOPE 0.01f
#define BT 256
#define CAP 80   // padded-CSR slots per node (mean deg 32, exp. max ~60); CAP%16==0

__device__ __forceinline__ float leakyf(float x){ return x >= 0.0f ? x : SLOPE*x; }
__device__ __forceinline__ float dleakyf(float x){ return x >= 0.0f ? 1.0f : SLOPE; }

__device__ __forceinline__ float red16(float v){
  v += __shfl_xor(v, 8, 16);
  v += __shfl_xor(v, 4, 16);
  v += __shfl_xor(v, 2, 16);
  v += __shfl_xor(v, 1, 16);
  return v;
}

// fused: pos repack + analytic padded offsets
__global__ void k_pos4_off(const float* __restrict__ pos, float4* __restrict__ pos4,
                           int* __restrict__ off_row, int* __restrict__ off_col,
                           int use_pad){
  int n = blockIdx.x*blockDim.x + threadIdx.x;
  if (n >= NN) return;
  pos4[n] = make_float4(pos[3*n+0], pos[3*n+1], pos[3*n+2], 0.0f);
  if (use_pad){ off_row[n] = n*CAP; off_col[n] = n*CAP; }
}

// ---- CSR build, compact path (count + scan + place) ----------------------
__global__ void k_count(const int* __restrict__ ei, int* __restrict__ cnt_row,
                        int* __restrict__ cnt_col){
  int t = blockIdx.x*blockDim.x + threadIdx.x;
  if (t >= NE/4) return;
  int4 r4 = ((const int4*)ei)[t];
  int4 c4 = ((const int4*)(ei + NE))[t];
  atomicAdd(&cnt_row[r4.x], 1); atomicAdd(&cnt_row[r4.y], 1);
  atomicAdd(&cnt_row[r4.z], 1); atomicAdd(&cnt_row[r4.w], 1);
  atomicAdd(&cnt_col[c4.x], 1); atomicAdd(&cnt_col[c4.y], 1);
  atomicAdd(&cnt_col[c4.z], 1); atomicAdd(&cnt_col[c4.w], 1);
}

__global__ void k_blocksum(const int* __restrict__ cnt_row, const int* __restrict__ cnt_col,
                           int* __restrict__ bsum){
  const int* src = blockIdx.y ? cnt_col : cnt_row;
  __shared__ int s[BT];
  int i = blockIdx.x*BT + threadIdx.x;
  s[threadIdx.x] = (i < NN) ? src[i] : 0;
  __syncthreads();
  for (int off = BT/2; off > 0; off >>= 1){
    if (threadIdx.x < off) s[threadIdx.x] += s[threadIdx.x+off];
    __syncthreads();
  }
  if (threadIdx.x == 0) bsum[blockIdx.y*512 + blockIdx.x] = s[0];
}

__global__ void k_scan_bsum(int* __restrict__ bsum, int nb){
  int* b = bsum + blockIdx.y*512;
  __shared__ int s0[512], s1[512];
  int tid = threadIdx.x;
  int v = (tid < nb) ? b[tid] : 0;
  s0[tid] = v; __syncthreads();
  int rd = 0;
  for (int off = 1; off < 512; off <<= 1){
    int x = rd ? s1[tid] : s0[tid];
    if (tid >= off) x += rd ? s1[tid-off] : s0[tid-off];
    if (rd) s0[tid] = x; else s1[tid] = x;
    __syncthreads();
    rd ^= 1;
  }
  int incl = rd ? s1[tid] : s0[tid];
  if (tid < nb) b[tid] = incl - v;
}

__global__ void k_offsets(const int* __restrict__ cnt_row, const int* __restrict__ cnt_col,
                          const int* __restrict__ bsum,
                          int* __restrict__ off_row, int* __restrict__ off_col,
                          int* __restrict__ cur_row, int* __restrict__ cur_col){
  const int* src  = blockIdx.y ? cnt_col : cnt_row;
  int* offd = blockIdx.y ? off_col : off_row;
  int* curd = blockIdx.y ? cur_col : cur_row;
  __shared__ int s0[BT], s1[BT];
  int tid = threadIdx.x;
  int i = blockIdx.x*BT + tid;
  int v = (i < NN) ? src[i] : 0;
  s0[tid] = v; __syncthreads();
  int rd = 0;
  for (int off = 1; off < BT; off <<= 1){
    int x = rd ? s1[tid] : s0[tid];
    if (tid >= off) x += rd ? s1[tid-off] : s0[tid-off];
    if (rd) s0[tid] = x; else s1[tid] = x;
    __syncthreads();
    rd ^= 1;
  }
  int incl = rd ? s1[tid] : s0[tid];
  if (i < NN){
    int o = bsum[blockIdx.y*512 + blockIdx.x] + incl - v;
    offd[i] = o; curd[i] = o;
  }
}

// SoA scattered 4B stores (measured fastest layout, r2 vs r3)
__global__ void k_place(const int* __restrict__ ei, const float4* __restrict__ pos4,
                        int* __restrict__ cur_row, int* __restrict__ cur_col,
                        int* __restrict__ row_dst, float* __restrict__ row_w,
                        int* __restrict__ col_src, int* __restrict__ col_rp,
                        float* __restrict__ col_w){
  int e = blockIdx.x*blockDim.x + threadIdx.x;
  if (e >= NE) return;
  int r = ei[e], c = ei[NE+e];
  float4 pr = pos4[r], pc = pos4[c];
  float dx = pr.x-pc.x, dy = pr.y-pc.y, dz = pr.z-pc.z;
  float w = sqrtf(dx*dx+dy*dy+dz*dz);
  int p = atomicAdd(&cur_row[r], 1);
  int q = atomicAdd(&cur_col[c], 1);
  row_dst[p] = c; row_w[p] = w;
  col_src[q] = r; col_rp[q] = p; col_w[q] = w;
}

// ---- CSR build, padded path (no count/scan; base = n*CAP) ----------------
__global__ void k_place_pad(const int* __restrict__ ei, const float4* __restrict__ pos4,
                            int* __restrict__ cnt_row, int* __restrict__ cnt_col,
                            int* __restrict__ row_dst, float* __restrict__ row_w,
                            int* __restrict__ col_src, int* __restrict__ col_rp,
                            float* __restrict__ col_w){
  int e = blockIdx.x*blockDim.x + threadIdx.x;
  if (e >= NE) return;
  int r = ei[e], c = ei[NE+e];
  float4 pr = pos4[r], pc = pos4[c];
  float dx = pr.x-pc.x, dy = pr.y-pc.y, dz = pr.z-pc.z;
  float w = sqrtf(dx*dx+dy*dy+dz*dz);
  int p = r*CAP + atomicAdd(&cnt_row[r], 1);
  int q = c*CAP + atomicAdd(&cnt_col[c], 1);
  row_dst[p] = c; row_w[p] = w;
  col_src[q] = r; col_rp[q] = p; col_w[q] = w;
}

// zero-fill pad slots [cnt, roundup16(cnt)) so block loops can skip tails.
// src/dst=0 (valid index), w=0 (nullifies every weighted contribution).
__global__ void k_padzero(const int* __restrict__ cnt_row, const int* __restrict__ cnt_col,
                          int* __restrict__ row_dst, float* __restrict__ row_w,
                          int* __restrict__ col_src, float* __restrict__ col_w){
  int t = blockIdx.x*blockDim.x + threadIdx.x;
  int n = t >> 4, k = t & 15;
  if (n >= NN) return;
  int cr = cnt_row[n], er = (cr + 15) & ~15;
  if (cr + k < er){ row_dst[n*CAP + cr + k] = 0; row_w[n*CAP + cr + k] = 0.f; }
  int cc = cnt_col[n], ec = (cc + 15) & ~15;
  if (cc + k < ec){ col_src[n*CAP + cc + k] = 0; col_w[n*CAP + cc + k] = 0.f; }
}

// ---- forward ------------------------------------------------------------
__global__ void k_dinv_y1(const float* __restrict__ col_w, const int* __restrict__ off_col,
                          const int* __restrict__ cnt_col,
                          const float* __restrict__ emb, const int* __restrict__ z,
                          const float* __restrict__ W1,
                          float* __restrict__ dinv, float* __restrict__ ys1){
  __shared__ float sW[D*D];
  for (int i = threadIdx.x; i < D*D; i += blockDim.x) sW[i] = W1[i];
  __syncthreads();
  int t = blockIdx.x*blockDim.x + threadIdx.x;
  int n = t >> 4, k = t & 15;
  if (n >= NN) return;
  int base = off_col[n], cnt = cnt_col[n];
  float s = 0.f;
  for (int i = k; i < cnt; i += 16) s += col_w[base+i];
  s = red16(s);
  float dv = 1.0f / sqrtf(1.0f + s);
  if (k == 0) dinv[n] = dv;
  float h = emb[z[n]*D + k];
  float acc = 0.f;
  #pragma unroll
  for (int j = 0; j < D; j++) acc += __shfl(h, j, 16)*sW[j*D+k];
  ys1[n*D+k] = dv*acc;
}

// conv1 gather (16-edge blocks; pad16 -> no tail) + MLP mid
__global__ void k_conv1_mid(const int* __restrict__ col_src, const float* __restrict__ col_w,
                            const int* __restrict__ off_col, const int* __restrict__ cnt_col,
                            const float* __restrict__ dinv, const float* __restrict__ ys1,
                            const float* __restrict__ b1, const float* __restrict__ Wl1,
                            const float* __restrict__ bl1, const float* __restrict__ W2,
                            float* __restrict__ ys2, unsigned* __restrict__ masks,
                            int pad16){
  __shared__ float sWl1[D*D], sW2[D*D], sb1[D], sbl1[D];
  for (int i = threadIdx.x; i < D*D; i += blockDim.x){ sWl1[i] = Wl1[i]; sW2[i] = W2[i]; }
  if (threadIdx.x < D){ sb1[threadIdx.x] = b1[threadIdx.x]; sbl1[threadIdx.x] = bl1[threadIdx.x]; }
  __syncthreads();
  int t = blockIdx.x*blockDim.x + threadIdx.x;
  int n = t >> 4, k = t & 15;
  if (n >= NN) return;
  int base = off_col[n], cnt = cnt_col[n];
  int cend = (cnt + (pad16 ? 15 : 0)) & ~15;
  float acc = 0.f;
  int i = 0;
  for (; i < cend; i += 16){
    int   se = col_src[base+i+k];   // coalesced: 16 lanes, 16 consecutive edges
    float we = col_w[base+i+k];
    #pragma unroll
    for (int j = 0; j < 16; j++){
      int   sj = __shfl(se, j, 16);
      float wj = __shfl(we, j, 16);
      acc += wj * ys1[sj*D+k];
    }
  }
  for (; i < cnt; i++)
    acc += col_w[base+i]*ys1[col_src[base+i]*D+k];
  float dv = dinv[n];
  float u1 = dv*(acc + ys1[n*D+k]) + sb1[k];
  float h1 = leakyf(u1);
  float u2 = sbl1[k];
  #pragma unroll
  for (int j = 0; j < D; j++) u2 += __shfl(h1, j, 16)*sWl1[j*D+k];
  float h2 = leakyf(u2);
  float yo = 0.f;
  #pragma unroll
  for (int j = 0; j < D; j++) yo += __shfl(h2, j, 16)*sW2[j*D+k];
  ys2[n*D+k] = dv*yo;
  unsigned mm = ((u1 >= 0.f) ? (1u<<k) : 0u) | ((u2 >= 0.f) ? (1u<<(16+k)) : 0u);
  mm |= (unsigned)__shfl_xor((int)mm, 8, 16);
  mm |= (unsigned)__shfl_xor((int)mm, 4, 16);
  mm |= (unsigned)__shfl_xor((int)mm, 2, 16);
  mm |= (unsigned)__shfl_xor((int)mm, 1, 16);
  if (k == 0) masks[n] = mm;
}

// conv2 gather (16-edge blocks) + head + energy + head backward: ds3, gdiag_s
__global__ void k_conv2_out(const int* __restrict__ col_src, const float* __restrict__ col_w,
                            const int* __restrict__ off_col, const int* __restrict__ cnt_col,
                            const float* __restrict__ dinv, const float* __restrict__ ys2,
                            const int* __restrict__ batch,
                            const float* __restrict__ b2, const float* __restrict__ Wl2,
                            const float* __restrict__ bl2, const float* __restrict__ Wl3,
                            const float* __restrict__ bl3,
                            float* __restrict__ Eout, float* __restrict__ ds3,
                            float* __restrict__ gdiag, int pad16){
  __shared__ float sWl2[D*4], sb2[D], sbl2[4], sWl3[4], sbl3s;
  if (threadIdx.x < D*4) sWl2[threadIdx.x] = Wl2[threadIdx.x];
  if (threadIdx.x < D) sb2[threadIdx.x] = b2[threadIdx.x];
  if (threadIdx.x < 4){ sbl2[threadIdx.x] = bl2[threadIdx.x]; sWl3[threadIdx.x] = Wl3[threadIdx.x]; }
  if (threadIdx.x == 0) sbl3s = bl3[0];
  __syncthreads();
  int t = blockIdx.x*blockDim.x + threadIdx.x;
  int n = t >> 4, k = t & 15;
  if (n >= NN) return;
  int base = off_col[n], cnt = cnt_col[n];
  int cend = (cnt + (pad16 ? 15 : 0)) & ~15;
  float acc = 0.f;
  int i = 0;
  for (; i < cend; i += 16){
    int   se = col_src[base+i+k];
    float we = col_w[base+i+k];
    #pragma unroll
    for (int j = 0; j < 16; j++){
      int   sj = __shfl(se, j, 16);
      float wj = __shfl(we, j, 16);
      acc += wj * ys2[sj*D+k];
    }
  }
  for (; i < cnt; i++)
    acc += col_w[base+i]*ys2[col_src[base+i]*D+k];
  float dv = dinv[n];
  float ysk = ys2[n*D+k];
  float u3 = dv*(acc + ysk) + sb2[k];
  float h3 = leakyf(u3);
  float u40 = sbl2[0], u41 = sbl2[1], u42 = sbl2[2], u43 = sbl2[3];
  #pragma unroll
  for (int j = 0; j < D; j++){
    float hj = __shfl(h3, j, 16);
    u40 += hj*sWl2[j*4+0]; u41 += hj*sWl2[j*4+1];
    u42 += hj*sWl2[j*4+2]; u43 += hj*sWl2[j*4+3];
  }
  float h40 = leakyf(u40), h41 = leakyf(u41), h42 = leakyf(u42), h43 = leakyf(u43);
  float u5 = sbl3s + h40*sWl3[0] + h41*sWl3[1] + h42*sWl3[2] + h43*sWl3[3];
  float h5 = leakyf(u5);
  if (k == 0) atomicAdd(&Eout[batch[n]], h5);
  float du5 = dleakyf(u5);
  float d40 = du5*sWl3[0]*dleakyf(u40);
  float d41 = du5*sWl3[1]*dleakyf(u41);
  float d42 = du5*sWl3[2]*dleakyf(u42);
  float d43 = du5*sWl3[3]*dleakyf(u43);
  float g = d40*sWl2[k*4+0] + d41*sWl2[k*4+1] + d42*sWl2[k*4+2] + d43*sWl2[k*4+3];
  float d3 = g*dleakyf(u3);
  ds3[n*D+k] = dv*d3;
  float gd = red16(d3*ysk);          // gdiag_s = dv * (du3 . y2)
  if (k == 0) gdiag[n] = gd;
}

// ---- backward -----------------------------------------------------------
// FUSED row pass 2 + node mid chain. Pad-slot gn writes are finite garbage,
// only ever multiplied by w=0 downstream.
__global__ void k_bwd2mid(const int* __restrict__ row_dst, const float* __restrict__ row_w,
                          const int* __restrict__ off_row, const int* __restrict__ cnt_row,
                          const float* __restrict__ dinv, const float* __restrict__ ys1,
                          const float* __restrict__ ys2, const float* __restrict__ ds3,
                          const unsigned* __restrict__ masks,
                          const float* __restrict__ W2, const float* __restrict__ Wl1,
                          float* __restrict__ gn_row, float* __restrict__ ds1,
                          float* __restrict__ gdiag, int pad16){
  __shared__ float sW2[D*D], sWl1[D*D];
  for (int i = threadIdx.x; i < D*D; i += blockDim.x){ sW2[i] = W2[i]; sWl1[i] = Wl1[i]; }
  __syncthreads();
  int t = blockIdx.x*blockDim.x + threadIdx.x;
  int n = t >> 4, k = t & 15;
  if (n >= NN) return;
  int base = off_row[n], cnt = cnt_row[n];
  int cend = (cnt + (pad16 ? 15 : 0)) & ~15;
  float ysk = ys2[n*D+k];
  float gacc = 0.f;
  int i = 0;
  for (; i < cend; i += 16){
    int   ce = row_dst[base+i+k];
    float we = row_w[base+i+k];
    float myg = 0.f;
    #pragma unroll
    for (int j = 0; j < 16; j++){
      int   cj = __shfl(ce, j, 16);
      float wj = __shfl(we, j, 16);
      float dval = ds3[cj*D+k];
      gacc += wj*dval;
      float p = red16(dval*ysk);
      if (j == k) myg = p;
    }
    gn_row[base+i+k] = myg;          // coalesced store
  }
  for (; i < cnt; i++){
    int c = row_dst[base+i];
    float dval = ds3[c*D+k];
    gacc += row_w[base+i]*dval;
    float p = red16(dval*ysk);
    if (k == 0) gn_row[base+i] = p;
  }
  float dv = dinv[n];
  unsigned m = masks[n];
  float gy = dv*gacc + dv*ds3[n*D+k];      // gy2 + d2*du3
  float du2 = 0.f;
  #pragma unroll
  for (int j = 0; j < D; j++) du2 += __shfl(gy, j, 16)*sW2[k*D+j];
  du2 *= ((m>>(16+k))&1u) ? 1.0f : SLOPE;
  float du1 = 0.f;
  #pragma unroll
  for (int j = 0; j < D; j++) du1 += __shfl(du2, j, 16)*sWl1[k*D+j];
  du1 *= ((m>>k)&1u) ? 1.0f : SLOPE;
  float gd = red16(du1*ys1[n*D+k]);        // adds dv*(du1 . y1)
  if (k == 0) gdiag[n] += gd;
  ds1[n*D+k] = dv*du1;
}

// row pass 1: gn_row += ds1[c].ys1[n]; gdinv_row = sum gn*w (pad: w=0 kills it)
__global__ void k_bwd1row(const int* __restrict__ row_dst, const float* __restrict__ row_w,
                          const int* __restrict__ off_row, const int* __restrict__ cnt_row,
                          const float* __restrict__ ys1, const float* __restrict__ ds1,
                          float* __restrict__ gn_row, float* __restrict__ gdinv_row,
                          int pad16){
  int t = blockIdx.x*blockDim.x + threadIdx.x;
  int n = t >> 4, k = t & 15;
  if (n >= NN) return;
  int base = off_row[n], cnt = cnt_row[n];
  int cend = (cnt + (pad16 ? 15 : 0)) & ~15;
  float ysk = ys1[n*D+k];
  float gdr = 0.f;
  int i = 0;
  for (; i < cend; i += 16){
    int   ce = row_dst[base+i+k];
    float we = row_w[base+i+k];
    float gold = gn_row[base+i+k];   // coalesced read
    float myg = 0.f;
    #pragma unroll
    for (int j = 0; j < 16; j++){
      int   cj = __shfl(ce, j, 16);
      float wj = __shfl(we, j, 16);
      float dval = ds1[cj*D+k];
      float p = red16(dval*ysk);
      float gj = __shfl(gold, j, 16) + p;
      if (j == k) myg = gj;
      gdr += gj*wj;
    }
    gn_row[base+i+k] = myg;          // coalesced store
  }
  for (; i < cnt; i++){
    int c = row_dst[base+i];
    float dval = ds1[c*D+k];
    float p = red16(dval*ysk);
    float g = gn_row[base+i] + p;
    if (k == 0) gn_row[base+i] = g;
    gdr += g*row_w[base+i];
  }
  if (k == 0) gdinv_row[n] = gdr;
}

// col pass: gns_col copy (contiguous write), gdeg, packed node table (pos, gdeg)
__global__ void k_gdeg(const int* __restrict__ col_rp, const float* __restrict__ col_w,
                       const int* __restrict__ off_col, const int* __restrict__ cnt_col,
                       const float* __restrict__ gn_row, const float* __restrict__ gdinv_row,
                       const float* __restrict__ gdiag, const float* __restrict__ dinv,
                       const float4* __restrict__ pos4,
                       float* __restrict__ gns_col, float4* __restrict__ pn4){
  int t = blockIdx.x*blockDim.x + threadIdx.x;
  int n = t >> 4, k = t & 15;
  if (n >= NN) return;
  int base = off_col[n], cnt = cnt_col[n];
  float gc = 0.f;
  for (int i = k; i < cnt; i += 16){
    float g = gn_row[col_rp[base+i]];
    gc += g*col_w[base+i];
    gns_col[base+i] = g;
  }
  gc = red16(gc);
  if (k == 0){
    float dv = dinv[n];
    float arg = (gdinv_row[n] + gc)/dv + 2.0f*gdiag[n];  // gdiag holds dv*gdiag_true
    float gd = -0.5f*dv*dv*dv*arg;
    float4 p = pos4[n];
    pn4[n] = make_float4(p.x, p.y, p.z, gd);
  }
}

// force gather: coef = (gns + gdeg[col-node])/w, both directions (true cnt only)
__global__ void k_force(const int* __restrict__ row_dst, const float* __restrict__ row_w,
                        const int* __restrict__ off_row, const int* __restrict__ cnt_row,
                        const int* __restrict__ col_src, const float* __restrict__ col_w,
                        const int* __restrict__ off_col, const int* __restrict__ cnt_col,
                        const float* __restrict__ gn_row, const float* __restrict__ gns_col,
                        const float4* __restrict__ pn4, float* __restrict__ F){
  int t = blockIdx.x*blockDim.x + threadIdx.x;
  int n = t >> 4, k = t & 15;
  if (n >= NN) return;
  float4 pn = pn4[n];
  float fx = 0.f, fy = 0.f, fz = 0.f;
  int base = off_row[n], cnt = cnt_row[n];
  for (int i = k; i < cnt; i += 16){
    int c = row_dst[base+i];
    float g = gn_row[base+i];
    float4 pc = pn4[c];
    float coef = (g + pc.w)/row_w[base+i];
    fx -= coef*(pn.x-pc.x); fy -= coef*(pn.y-pc.y); fz -= coef*(pn.z-pc.z);
  }
  base = off_col[n]; cnt = cnt_col[n];
  for (int i = k; i < cnt; i += 16){
    int r = col_src[base+i];
    float g = gns_col[base+i];
    float4 pr = pn4[r];
    float coef = (g + pn.w)/col_w[base+i];
    fx += coef*(pr.x-pn.x); fy += coef*(pr.y-pn.y); fz += coef*(pr.z-pn.z);
  }
  fx = red16(fx); fy = red16(fy); fz = red16(fz);
  if (k == 0){ F[3*n+0] = fx; F[3*n+1] = fy; F[3*n+2] = fz; }
}

extern "C" void kernel_launch(void* const* d_in, const int* in_sizes, int n_in,
                              void* d_out, int out_size, void* d_ws, size_t ws_size,
                              hipStream_t stream){
  const float* pos = (const float*)d_in[0];
  const float* emb = (const float*)d_in[1];
  const float* W1  = (const float*)d_in[2];
  const float* b1  = (const float*)d_in[3];
  const float* Wl1 = (const float*)d_in[4];
  const float* bl1 = (const float*)d_in[5];
  const float* W2  = (const float*)d_in[6];
  const float* b2  = (const float*)d_in[7];
  const float* Wl2 = (const float*)d_in[8];
  const float* bl2 = (const float*)d_in[9];
  const float* Wl3 = (const float*)d_in[10];
  const float* bl3 = (const float*)d_in[11];
  const int* z     = (const int*)d_in[12];
  const int* ei    = (const int*)d_in[13];
  const int* batch = (const int*)d_in[14];

  // padded layout needs ~78N + 1024 + 7*CAP*N words (~255 MB); gate on ws_size
  size_t need_pad = 4ull*((size_t)78*NN + 1024 + 7ull*CAP*NN);
  bool padded = (ws_size >= need_pad);
  size_t ER = padded ? (size_t)CAP*NN : (size_t)NE;   // edge-array length
  int pad16 = padded ? 1 : 0;

  char* base = (char*)d_ws;
  size_t o = 0;
  auto alloc = [&](size_t words){ o = (o + 15) & ~(size_t)15; void* p = base + o*4; o += words; return p; };
  int*   cnt_row   = (int*)alloc(NN);
  int*   cnt_col   = (int*)alloc(NN);
  int*   off_row   = (int*)alloc(NN);
  int*   off_col   = (int*)alloc(NN);
  int*   cur_row   = (int*)alloc(NN);
  int*   cur_col   = (int*)alloc(NN);
  int*   bsum      = (int*)alloc(1024);
  float* dinv      = (float*)alloc(NN);
  float* gdiag     = (float*)alloc(NN);
  float* gdinv_row = (float*)alloc(NN);
  unsigned* masks  = (unsigned*)alloc(NN);
  float4* pos4     = (float4*)alloc(4*NN);
  float* ys1       = (float*)alloc(16*NN);
  float* ys2       = (float*)alloc(16*NN);
  float* ds3       = (float*)alloc(16*NN);
  float* ds1       = (float*)alloc(16*NN);
  int*   row_dst   = (int*)alloc(ER);
  float* row_w     = (float*)alloc(ER);
  int*   col_src   = (int*)alloc(ER);
  int*   col_rp    = (int*)alloc(ER);
  float* col_w     = (float*)alloc(ER);
  float* gn_row    = (float*)alloc(ER);
  // gns_col: padded path allocates; compact path aliases ys1+ys2 (E == 32N,
  // both dead after k_bwd1row). pn4 aliases ds3 (dead after k_bwd2mid).
  float*  gns_col = padded ? (float*)alloc(ER) : ys1;
  float4* pn4     = (float4*)ds3;

  float* Eout = (float*)d_out;
  float* F = Eout + NG;

  int nbN   = (NN + BT - 1)/BT;        // 391
  int nbE   = (NE + BT - 1)/BT;
  int nbE4  = (NE/4 + BT - 1)/BT;
  int nbN16 = (NN*16 + BT - 1)/BT;     // 6250

  hipMemsetAsync(cnt_row, 0, 2*(size_t)NN*4, stream);
  hipMemsetAsync(Eout, 0, (size_t)NG*4, stream);

  k_pos4_off<<<nbN, BT, 0, stream>>>(pos, pos4, off_row, off_col, pad16);

  // CSR build
  if (padded){
    k_place_pad<<<nbE, BT, 0, stream>>>(ei, pos4, cnt_row, cnt_col,
                                        row_dst, row_w, col_src, col_rp, col_w);
    k_padzero<<<nbN16, BT, 0, stream>>>(cnt_row, cnt_col,
                                        row_dst, row_w, col_src, col_w);
  } else {
    k_count<<<nbE4, BT, 0, stream>>>(ei, cnt_row, cnt_col);
    k_blocksum<<<dim3(nbN,2), BT, 0, stream>>>(cnt_row, cnt_col, bsum);
    k_scan_bsum<<<dim3(1,2), 512, 0, stream>>>(bsum, nbN);
    k_offsets<<<dim3(nbN,2), BT, 0, stream>>>(cnt_row, cnt_col, bsum,
                                              off_row, off_col, cur_row, cur_col);
    k_place<<<nbE, BT, 0, stream>>>(ei, pos4, cur_row, cur_col,
                                    row_dst, row_w, col_src, col_rp, col_w);
  }

  // forward
  k_dinv_y1<<<nbN16, BT, 0, stream>>>(col_w, off_col, cnt_col, emb, z, W1, dinv, ys1);
  k_conv1_mid<<<nbN16, BT, 0, stream>>>(col_src, col_w, off_col, cnt_col, dinv, ys1,
                                        b1, Wl1, bl1, W2, ys2, masks, pad16);
  k_conv2_out<<<nbN16, BT, 0, stream>>>(col_src, col_w, off_col, cnt_col, dinv, ys2,
                                        batch, b2, Wl2, bl2, Wl3, bl3, Eout, ds3,
                                        gdiag, pad16);

  // backward
  k_bwd2mid<<<nbN16, BT, 0, stream>>>(row_dst, row_w, off_row, cnt_row, dinv, ys1, ys2,
                                      ds3, masks, W2, Wl1, gn_row, ds1, gdiag, pad16);
  k_bwd1row<<<nbN16, BT, 0, stream>>>(row_dst, row_w, off_row, cnt_row, ys1, ds1,
                                      gn_row, gdinv_row, pad16);
  k_gdeg<<<nbN16, BT, 0, stream>>>(col_rp, col_w, off_col, cnt_col, gn_row, gdinv_row,
                                   gdiag, dinv, pos4, gns_col, pn4);
  k_force<<<nbN16, BT, 0, stream>>>(row_dst, row_w, off_row, cnt_row,
                                    col_src, col_w, off_col, cnt_col,
                                    gn_row, gns_col, pn4, F);
}